// Round 5
// baseline (569.997 us; speedup 1.0000x reference)
//
#include <hip/hip_runtime.h>

// Pipeline (node features packed bf16 pairs; word c = channels 2c,2c+1):
//  init -> pcount (per-wave per-partition edge counts) -> scan(pcnt)
//  -> ppart (multisplit edges into 8 dst-partitions, ballot-ranked, no atomics)
//  -> hist (per-XCD partition, L2-local) -> dinv -> scan(counts)
//  -> scatter (per-XCD partition counting sort -> sorted[] CSR)
//  -> gemm_mfma<f32 A> (hb = bf16(x@W1); b1 cancels in BN)
//  -> gather (agg1b bf16) -> bn_stats -> bn_relu (in place)
//  -> gemm_mfma<bf16 A> (hb) -> gather (aggb)
//  -> gstart -> pool (+b2) -> head

typedef __attribute__((ext_vector_type(8))) short bf16x8;
typedef __attribute__((ext_vector_type(4))) float f32x4;

#define NPART 8
#define NW_SPLIT 4096  // waves in pcount/ppart (1024 blocks x 4 waves)

__device__ __forceinline__ float bf_lo(unsigned u) {
  union { unsigned u; float f; } c; c.u = u << 16; return c.f;
}
__device__ __forceinline__ float bf_hi(unsigned u) {
  union { unsigned u; float f; } c; c.u = u & 0xffff0000u; return c.f;
}
__device__ __forceinline__ unsigned short f32_bf16(float f) {
  union { float f; unsigned u; } c; c.f = f;
  return (unsigned short)((c.u + 0x7fffu + ((c.u >> 16) & 1u)) >> 16);  // RNE
}
__device__ __forceinline__ unsigned pack_bf16(float a, float b) {
  return (unsigned)f32_bf16(a) | ((unsigned)f32_bf16(b) << 16);
}

__global__ void init_kernel(int* __restrict__ counts, float* __restrict__ stats, int n) {
  int i = blockIdx.x * blockDim.x + threadIdx.x;
  if (i < n) counts[i] = 0;
  if (i < 256) stats[i] = 0.f;
}

// ---- multisplit phase A: per-wave per-partition counts (edges read once) ----
__global__ __launch_bounds__(256) void pcount_kernel(const int* __restrict__ dst,
                                                     int* __restrict__ pcnt,
                                                     int e, int n, int chunk) {
  int w = (int)((blockIdx.x * 256u + threadIdx.x) >> 6);
  int lane = threadIdx.x & 63;
  int beg = w * chunk;
  int end = beg + chunk; if (end > e) end = e;
  int cnt[NPART];
#pragma unroll
  for (int p = 0; p < NPART; ++p) cnt[p] = 0;
  for (int i0 = beg; i0 < end; i0 += 64) {
    int idx = i0 + lane;
    int pe = NPART;
    if (idx < end) {
      int d = __builtin_nontemporal_load(&dst[idx]);
      pe = (int)((8u * (unsigned)d) / (unsigned)n);
    }
#pragma unroll
    for (int p = 0; p < NPART; ++p) cnt[p] += __popcll(__ballot(pe == p));
  }
  if (lane == 0) {
#pragma unroll
    for (int p = 0; p < NPART; ++p) pcnt[p * NW_SPLIT + w] = cnt[p];
  }
}

// ---- multisplit phase C: append (src,dst) to exclusive ballot-ranked subranges ----
__global__ __launch_bounds__(256) void ppart_kernel(const int* __restrict__ src,
                                                    const int* __restrict__ dst,
                                                    const int* __restrict__ pscan,
                                                    int* __restrict__ psrc,
                                                    int* __restrict__ pdst,
                                                    int e, int n, int chunk) {
  int w = (int)((blockIdx.x * 256u + threadIdx.x) >> 6);
  int lane = threadIdx.x & 63;
  int off[NPART];
#pragma unroll
  for (int p = 0; p < NPART; ++p) off[p] = pscan[p * NW_SPLIT + w];
  int beg = w * chunk;
  int end = beg + chunk; if (end > e) end = e;
  unsigned long long below = ((unsigned long long)1 << lane) - 1ull;
  for (int i0 = beg; i0 < end; i0 += 64) {
    int idx = i0 + lane;
    int s = 0, d = 0, pe = NPART;
    if (idx < end) {
      s = __builtin_nontemporal_load(&src[idx]);
      d = __builtin_nontemporal_load(&dst[idx]);
      pe = (int)((8u * (unsigned)d) / (unsigned)n);
    }
#pragma unroll
    for (int p = 0; p < NPART; ++p) {
      unsigned long long m = __ballot(pe == p);
      int pos = off[p] + __popcll(m & below);
      if (pe == p) { psrc[pos] = s; pdst[pos] = d; }
      off[p] += __popcll(m);
    }
  }
}

__global__ void dinv_kernel(const int* __restrict__ counts, float* __restrict__ dinv, int n) {
  int i = blockIdx.x * blockDim.x + threadIdx.x;
  if (i < n) dinv[i] = rsqrtf((float)(counts[i] + 1));  // +1 self-loop
}

// ---- hierarchical exclusive scan ----
__global__ __launch_bounds__(1024) void scan1_kernel(const int* __restrict__ counts,
                                                     int* __restrict__ cursor,
                                                     int* __restrict__ bsum, int n) {
  __shared__ int wsum[16];
  int tid = threadIdx.x, lane = tid & 63, wid = tid >> 6;
  int idx = blockIdx.x * 1024 + tid;
  int orig = (idx < n) ? counts[idx] : 0;
  int v = orig;
#pragma unroll
  for (int d = 1; d < 64; d <<= 1) {
    int t = __shfl_up(v, d, 64);
    if (lane >= d) v += t;
  }
  if (lane == 63) wsum[wid] = v;
  __syncthreads();
  if (wid == 0 && lane < 16) {
    int s = wsum[lane];
#pragma unroll
    for (int d = 1; d < 16; d <<= 1) {
      int t = __shfl_up(s, d, 64);
      if (lane >= d) s += t;
    }
    wsum[lane] = s;
  }
  __syncthreads();
  int wexcl = (wid == 0) ? 0 : wsum[wid - 1];
  if (idx < n) cursor[idx] = wexcl + (v - orig);
  if (tid == 0) bsum[blockIdx.x] = wsum[15];
}

__global__ __launch_bounds__(256) void scan2_kernel(const int* __restrict__ bsum,
                                                    int* __restrict__ boff, int nb) {
  __shared__ int wsum[4];
  int tid = threadIdx.x, lane = tid & 63, wid = tid >> 6;
  int orig = (tid < nb) ? bsum[tid] : 0;
  int v = orig;
#pragma unroll
  for (int d = 1; d < 64; d <<= 1) {
    int t = __shfl_up(v, d, 64);
    if (lane >= d) v += t;
  }
  if (lane == 63) wsum[wid] = v;
  __syncthreads();
  if (tid == 0) {
    int run = 0;
#pragma unroll
    for (int w = 0; w < 4; ++w) { int t = wsum[w]; wsum[w] = run; run += t; }
  }
  __syncthreads();
  if (tid < nb) boff[tid] = wsum[wid] + (v - orig);
}

__global__ void scan3_kernel(int* __restrict__ cursor, const int* __restrict__ boff, int n) {
  int i = blockIdx.x * blockDim.x + threadIdx.x;
  if (i < n) cursor[i] += boff[i >> 10];
}

// ---- per-XCD-partition histogram: reads only its partition's dst stream ----
__global__ __launch_bounds__(256) void hist_kernel(const int* __restrict__ pdst,
                                                   const int* __restrict__ pscan,
                                                   int* __restrict__ counts, int e) {
  int part = blockIdx.x & 7;
  int rank = blockIdx.x >> 3;
  int nrank = gridDim.x >> 3;
  int beg = pscan[part * NW_SPLIT];
  int end = (part < 7) ? pscan[(part + 1) * NW_SPLIT] : e;
  for (int i = beg + rank * 256 + threadIdx.x; i < end; i += nrank * 256)
    atomicAdd(&counts[pdst[i]], 1);
}

// ---- per-XCD-partition counting-sort scatter (L2-local lines, no thrash) ----
__global__ __launch_bounds__(256) void scatter_kernel(const int* __restrict__ psrc,
                                                      const int* __restrict__ pdst,
                                                      const int* __restrict__ pscan,
                                                      int* __restrict__ cursor,
                                                      int* __restrict__ sorted_src, int e) {
  int part = blockIdx.x & 7;
  int rank = blockIdx.x >> 3;
  int nrank = gridDim.x >> 3;
  int beg = pscan[part * NW_SPLIT];
  int end = (part < 7) ? pscan[(part + 1) * NW_SPLIT] : e;
  for (int i = beg + rank * 256 + threadIdx.x; i < end; i += nrank * 256) {
    int d = pdst[i];
    int s = psrc[i];
    int pos = atomicAdd(&cursor[d], 1);
    sorted_src[pos] = s;
  }
  // post: cursor[i] == row_end(i); row_beg(i) = cursor[i] - counts[i]
}

// MFMA GEMM: Cb[n][64 words] = bf16(A[n][128] @ W[128][128]).
template <bool ABF16>
__global__ __launch_bounds__(256) void gemm_mfma_kernel(const void* __restrict__ Ap,
                                                        const float* __restrict__ W,
                                                        unsigned* __restrict__ Cb, int n) {
  __shared__ unsigned short WB[16384];  // [kt][ct][nl][q][8 bf16] = 32 KB
  int tid = threadIdx.x;
  for (int idx = tid; idx < 16384; idx += 256) {
    int k = idx >> 7, c = idx & 127;  // W[k][c]
    int kt = k >> 5, q = (k >> 3) & 3, j = k & 7;
    int ct = c >> 4, nl = c & 15;
    WB[(((kt * 8 + ct) * 16 + nl) * 4 + q) * 8 + j] = f32_bf16(W[idx]);
  }
  __syncthreads();
  int lane = tid & 63;
  int m = lane & 15, q = lane >> 4;
  int wv = (int)((blockIdx.x * 256u + tid) >> 6);
  int nwv = (int)((gridDim.x * 256u) >> 6);
  int ntiles = n >> 4;  // n % 16 == 0 here (100000)
  for (int t = wv; t < ntiles; t += nwv) {
    int row = t * 16 + m;
    bf16x8 af[4];
    if (ABF16) {
      const bf16x8* Ar = (const bf16x8*)((const unsigned*)Ap + (size_t)row * 64 + q * 4);
#pragma unroll
      for (int kt = 0; kt < 4; ++kt) af[kt] = Ar[kt * 4];
    } else {
      const float* Arow = (const float*)Ap + (size_t)row * 128 + q * 8;
#pragma unroll
      for (int kt = 0; kt < 4; ++kt) {
        f32x4 a0 = *(const f32x4*)(Arow + kt * 32);
        f32x4 a1 = *(const f32x4*)(Arow + kt * 32 + 4);
        union { bf16x8 v; unsigned short s[8]; } u;
        u.s[0] = f32_bf16(a0.x); u.s[1] = f32_bf16(a0.y);
        u.s[2] = f32_bf16(a0.z); u.s[3] = f32_bf16(a0.w);
        u.s[4] = f32_bf16(a1.x); u.s[5] = f32_bf16(a1.y);
        u.s[6] = f32_bf16(a1.z); u.s[7] = f32_bf16(a1.w);
        af[kt] = u.v;
      }
    }
    f32x4 acc[8];
#pragma unroll
    for (int ct = 0; ct < 8; ++ct) acc[ct] = (f32x4){0.f, 0.f, 0.f, 0.f};
#pragma unroll
    for (int kt = 0; kt < 4; ++kt) {
#pragma unroll
      for (int ct = 0; ct < 8; ++ct) {
        bf16x8 b = *(const bf16x8*)&WB[(((kt * 8 + ct) * 16 + m) * 4 + q) * 8];
        acc[ct] = __builtin_amdgcn_mfma_f32_16x16x32_bf16(af[kt], b, acc[ct], 0, 0, 0);
      }
    }
#pragma unroll
    for (int ct = 0; ct < 8; ++ct) {
#pragma unroll
      for (int r4 = 0; r4 < 4; ++r4) {
        float v = acc[ct][r4];
        float p = __shfl_xor(v, 1, 64);
        if (!(m & 1)) {
          int r = t * 16 + q * 4 + r4;
          Cb[(size_t)r * 64 + ct * 8 + (m >> 1)] = pack_bf16(v, p);
        }
      }
    }
  }
}

// agg[i] = dinv[i] * ( sum_e dinv[src]*h[src] + dinv[i]*h[i] ); packed bf16 in/out.
__global__ __launch_bounds__(256) void gather_kernel(const unsigned* __restrict__ h,
    const int* __restrict__ srcs, const int* __restrict__ cursor,
    const int* __restrict__ counts, const float* __restrict__ dinv,
    unsigned* __restrict__ out, int n) {
  int lane = threadIdx.x & 63;
  int gw = (int)((blockIdx.x * blockDim.x + threadIdx.x) >> 6);
  int nw = (int)((gridDim.x * blockDim.x) >> 6);
  for (int i0 = gw; i0 < n; i0 += nw) {
    int i = __builtin_amdgcn_readfirstlane(i0);
    int end = cursor[i];
    int cnt = counts[i];
    int beg = end - cnt;
    float di = dinv[i];
    unsigned hv = h[(size_t)i * 64 + lane];
    float ax = di * bf_lo(hv), ay = di * bf_hi(hv);  // self-loop
    int e = beg;
    for (; e + 4 <= end; e += 4) {
      int s0 = srcs[e];
      int s1 = srcs[e + 1];
      int s2 = srcs[e + 2];
      int s3 = srcs[e + 3];
      unsigned v0 = h[(size_t)s0 * 64 + lane];
      unsigned v1 = h[(size_t)s1 * 64 + lane];
      unsigned v2 = h[(size_t)s2 * 64 + lane];
      unsigned v3 = h[(size_t)s3 * 64 + lane];
      float w0 = dinv[s0], w1 = dinv[s1], w2 = dinv[s2], w3 = dinv[s3];
      ax = fmaf(w0, bf_lo(v0), ax); ay = fmaf(w0, bf_hi(v0), ay);
      ax = fmaf(w1, bf_lo(v1), ax); ay = fmaf(w1, bf_hi(v1), ay);
      ax = fmaf(w2, bf_lo(v2), ax); ay = fmaf(w2, bf_hi(v2), ay);
      ax = fmaf(w3, bf_lo(v3), ax); ay = fmaf(w3, bf_hi(v3), ay);
    }
    for (; e < end; ++e) {
      int s = srcs[e];
      unsigned v = h[(size_t)s * 64 + lane];
      float w = dinv[s];
      ax = fmaf(w, bf_lo(v), ax);
      ay = fmaf(w, bf_hi(v), ay);
    }
    out[(size_t)i * 64 + lane] = pack_bf16(di * ax, di * ay);
  }
}

__global__ __launch_bounds__(256) void bn_stats_kernel(const unsigned* __restrict__ a,
                                                       float* __restrict__ stats, int n) {
  int c2 = threadIdx.x & 63;
  int ph = threadIdx.x >> 6;
  float s0 = 0.f, s1 = 0.f, q0 = 0.f, q1 = 0.f;
  for (int r = blockIdx.x * 4 + ph; r < n; r += gridDim.x * 4) {
    unsigned v = a[(size_t)r * 64 + c2];
    float x0 = bf_lo(v), x1 = bf_hi(v);
    s0 += x0; s1 += x1; q0 += x0 * x0; q1 += x1 * x1;
  }
  __shared__ float ls[4][64][4];
  ls[ph][c2][0] = s0; ls[ph][c2][1] = s1; ls[ph][c2][2] = q0; ls[ph][c2][3] = q1;
  __syncthreads();
  if (threadIdx.x < 64) {
    int c = threadIdx.x;
    float S0 = 0.f, S1 = 0.f, Q0 = 0.f, Q1 = 0.f;
#pragma unroll
    for (int p = 0; p < 4; ++p) {
      S0 += ls[p][c][0]; S1 += ls[p][c][1]; Q0 += ls[p][c][2]; Q1 += ls[p][c][3];
    }
    atomicAdd(&stats[2 * c], S0);
    atomicAdd(&stats[2 * c + 1], S1);
    atomicAdd(&stats[128 + 2 * c], Q0);
    atomicAdd(&stats[129 + 2 * c], Q1);
  }
}

// In-place y = bf16(relu(gamma*(a-mu)*rstd + beta)); packed.
__global__ __launch_bounds__(256) void bn_relu_kernel(unsigned* __restrict__ a,
    const float* __restrict__ stats, const float* __restrict__ gamma,
    const float* __restrict__ beta, int n) {
  __shared__ float sc[128], sh[128];
  int tid = threadIdx.x;
  if (tid < 128) {
    float invN = 1.f / (float)n;
    float mu = stats[tid] * invN;
    float var = stats[128 + tid] * invN - mu * mu;
    float rstd = rsqrtf(var + 1e-5f);
    float s = gamma[tid] * rstd;
    sc[tid] = s;
    sh[tid] = beta[tid] - mu * s;
  }
  __syncthreads();
  size_t total = (size_t)n * 64;
  for (size_t w = blockIdx.x * (size_t)blockDim.x + tid; w < total;
       w += (size_t)gridDim.x * blockDim.x) {
    int c2 = (int)(w & 63);
    unsigned v = a[w];
    float y0 = fmaxf(fmaf(sc[2 * c2], bf_lo(v), sh[2 * c2]), 0.f);
    float y1 = fmaxf(fmaf(sc[2 * c2 + 1], bf_hi(v), sh[2 * c2 + 1]), 0.f);
    a[w] = pack_bf16(y0, y1);
  }
}

__global__ void gstart_kernel(const int* __restrict__ batch, int* __restrict__ gstart,
                              int n, int G) {
  int g = blockIdx.x * blockDim.x + threadIdx.x;
  if (g > G) return;
  if (g == G) { gstart[g] = n; return; }
  int lo = 0, hi = n;
  while (lo < hi) {
    int mid = (lo + hi) >> 1;
    if (batch[mid] < g) lo = mid + 1; else hi = mid;
  }
  gstart[g] = lo;
}

__global__ __launch_bounds__(256) void pool_kernel(const unsigned* __restrict__ a,
    const int* __restrict__ gstart, const float* __restrict__ b2,
    float* __restrict__ pooled, int G) {
  int g = blockIdx.x;
  int c2 = threadIdx.x & 63;
  int ph = threadIdx.x >> 6;
  int s = gstart[g], e = gstart[g + 1];
  float a0 = 0.f, a1 = 0.f;
  for (int r = s + ph; r < e; r += 4) {
    unsigned v = a[(size_t)r * 64 + c2];
    a0 += bf_lo(v); a1 += bf_hi(v);
  }
  __shared__ float ls[4][64][2];
  ls[ph][c2][0] = a0; ls[ph][c2][1] = a1;
  __syncthreads();
  if (threadIdx.x < 64) {
    int c = threadIdx.x;
    float S0 = 0.f, S1 = 0.f;
#pragma unroll
    for (int p = 0; p < 4; ++p) { S0 += ls[p][c][0]; S1 += ls[p][c][1]; }
    int cnt = e - s;
    float inv = (cnt > 0) ? 1.f / (float)cnt : 0.f;
    float2 res;
    res.x = (cnt > 0) ? (S0 * inv + b2[2 * c]) : 0.f;
    res.y = (cnt > 0) ? (S1 * inv + b2[2 * c + 1]) : 0.f;
    ((float2*)(pooled + (size_t)g * 128))[c] = res;
  }
}

__global__ __launch_bounds__(128) void head_kernel(const float* __restrict__ pooled,
    const float* __restrict__ rst, const float* __restrict__ Wg, const float* __restrict__ bg,
    const float* __restrict__ Wr, const float* __restrict__ br, const float* __restrict__ Wc,
    const float* __restrict__ bc, float* __restrict__ out, int G) {
  int g = blockIdx.x;
  int t = threadIdx.x;
  __shared__ float xc[128];
  if (t < 64) {
    float acc = bg[t];
    const float* __restrict__ p = pooled + (size_t)g * 128;
    for (int k = 0; k < 128; ++k) acc = fmaf(p[k], Wg[k * 64 + t], acc);
    xc[t] = fmaxf(acc, 0.f);
  } else {
    int j = t - 64;
    float acc = br[j];
    const float* __restrict__ r = rst + (size_t)g * 64;
    for (int k = 0; k < 64; ++k) acc = fmaf(r[k], Wr[k * 64 + j], acc);
    xc[t] = fmaxf(acc, 0.f);
  }
  __syncthreads();
  if (t < 2) {
    float acc = bc[t];
    for (int j = 0; j < 128; ++j) acc = fmaf(xc[j], Wc[j * 2 + t], acc);
    out[(size_t)g * 2 + t] = acc;
  }
}

extern "C" void kernel_launch(void* const* d_in, const int* in_sizes, int n_in,
                              void* d_out, int out_size, void* d_ws, size_t ws_size,
                              hipStream_t stream) {
  (void)n_in; (void)ws_size;
  const float* x     = (const float*)d_in[0];
  const int*   ei    = (const int*)d_in[1];
  const int*   batch = (const int*)d_in[2];
  const float* rst   = (const float*)d_in[3];
  const float* W1    = (const float*)d_in[5];
  // d_in[6] = b1 — cancels in BatchNorm, skipped
  const float* gamma = (const float*)d_in[7];
  const float* beta  = (const float*)d_in[8];
  const float* W2    = (const float*)d_in[9];
  const float* b2    = (const float*)d_in[10];
  const float* Wg    = (const float*)d_in[11];
  const float* bg    = (const float*)d_in[12];
  const float* Wr    = (const float*)d_in[13];
  const float* br    = (const float*)d_in[14];
  const float* Wc    = (const float*)d_in[15];
  const float* bc    = (const float*)d_in[16];
  float* out = (float*)d_out;

  int N = in_sizes[0] / 128;
  int E = in_sizes[1] / 2;
  int G = out_size / 2;
  const int* esrc = ei;
  const int* edst = ei + E;

  char* ws = (char*)d_ws;
  size_t off = 0;
  auto alloc = [&](size_t bytes) -> void* {
    void* p = ws + off;
    off += (bytes + 255) & ~(size_t)255;
    return p;
  };
  unsigned* hb  = (unsigned*)alloc((size_t)N * 64 * 4);  // packed bf16 h1/h2
  unsigned* agb = (unsigned*)alloc((size_t)N * 64 * 4);  // agg1b -> y1 (in place) -> agg2b
  int* sorted   = (int*)alloc((size_t)E * 4);
  int* psrc     = (int*)alloc((size_t)E * 4);            // partitioned src
  int* pdst     = (int*)alloc((size_t)E * 4);            // partitioned dst
  int* pcnt     = (int*)alloc((size_t)NPART * NW_SPLIT * 4);
  int* pscan    = (int*)alloc((size_t)NPART * NW_SPLIT * 4);
  int* counts   = (int*)alloc((size_t)N * 4);
  int* cursor   = (int*)alloc((size_t)N * 4);
  float* dinv   = (float*)alloc((size_t)N * 4);
  float* stats  = (float*)alloc(256 * 4);
  int* gstart   = (int*)alloc((size_t)(G + 1) * 4);
  float* pooled = (float*)alloc((size_t)G * 128 * 4);
  int* bsum     = (int*)alloc(256 * 4);
  int* boff     = (int*)alloc(256 * 4);
  int* pbsum    = (int*)alloc(256 * 4);
  int* pboff    = (int*)alloc(256 * 4);

  int nb = (N + 255) / 256;
  int nscan = (N + 1023) / 1024;
  int chunk = (E + NW_SPLIT - 1) / NW_SPLIT;
  int npsc = (NPART * NW_SPLIT) / 1024;  // 32

  init_kernel<<<nb, 256, 0, stream>>>(counts, stats, N);
  // multisplit: count -> scan -> partition
  pcount_kernel<<<NW_SPLIT / 4, 256, 0, stream>>>(edst, pcnt, E, N, chunk);
  scan1_kernel<<<npsc, 1024, 0, stream>>>(pcnt, pscan, pbsum, NPART * NW_SPLIT);
  scan2_kernel<<<1, 256, 0, stream>>>(pbsum, pboff, npsc);
  scan3_kernel<<<(NPART * NW_SPLIT) / 256, 256, 0, stream>>>(pscan, pboff, NPART * NW_SPLIT);
  ppart_kernel<<<NW_SPLIT / 4, 256, 0, stream>>>(esrc, edst, pscan, psrc, pdst, E, N, chunk);
  // CSR build (per-XCD partition, L2-local)
  hist_kernel<<<2048, 256, 0, stream>>>(pdst, pscan, counts, E);
  dinv_kernel<<<nb, 256, 0, stream>>>(counts, dinv, N);
  scan1_kernel<<<nscan, 1024, 0, stream>>>(counts, cursor, bsum, N);
  scan2_kernel<<<1, 256, 0, stream>>>(bsum, boff, nscan);
  scan3_kernel<<<(N + 255) / 256, 256, 0, stream>>>(cursor, boff, N);
  scatter_kernel<<<2048, 256, 0, stream>>>(psrc, pdst, pscan, cursor, sorted, E);

  gemm_mfma_kernel<false><<<1024, 256, 0, stream>>>(x, W1, hb, N);
  gather_kernel<<<4096, 256, 0, stream>>>(hb, sorted, cursor, counts, dinv, agb, N);

  bn_stats_kernel<<<512, 256, 0, stream>>>(agb, stats, N);
  bn_relu_kernel<<<2048, 256, 0, stream>>>(agb, stats, gamma, beta, N);

  gemm_mfma_kernel<true><<<1024, 256, 0, stream>>>(agb, W2, hb, N);
  gather_kernel<<<4096, 256, 0, stream>>>(hb, sorted, cursor, counts, dinv, agb, N);

  gstart_kernel<<<(G + 1 + 255) / 256, 256, 0, stream>>>(batch, gstart, N, G);
  pool_kernel<<<G, 256, 0, stream>>>(agb, gstart, b2, pooled, G);
  head_kernel<<<G, 128, 0, stream>>>(pooled, rst, Wg, bg, Wr, br, Wc, bc, out, G);
}

// Round 6
// 551.303 us; speedup vs baseline: 1.0339x; 1.0339x over previous
//
#include <hip/hip_runtime.h>

// Pipeline (node features packed bf16 pairs; word c = channels 2c,2c+1):
//  init -> pcount -> scan(pcnt) -> ppart (multisplit edges by dst partition, int2)
//  -> hist (per-XCD partition, L2-local) -> dinv -> scan(counts)
//  -> scatter (per-XCD partition counting sort -> sorted[] CSR)
//  -> gemm_mfma<f32 A> (g1 = dinv .* bf16(x@W1); b1 cancels in BN)
//  -> gather (agg1b = di*(sum g1[src] + g1[i]))
//  -> bn_stats -> bn_relu (in place)
//  -> gemm_mfma<bf16 A> (g2 = dinv .* bf16(y1@W2)) -> gather (agg2b)
//  -> gstart -> pool (+b2) -> head

typedef __attribute__((ext_vector_type(8))) short bf16x8;
typedef __attribute__((ext_vector_type(4))) float f32x4;

#define NPART 8
#define NW_SPLIT 4096  // waves in pcount/ppart (1024 blocks x 4 waves)

__device__ __forceinline__ float bf_lo(unsigned u) {
  union { unsigned u; float f; } c; c.u = u << 16; return c.f;
}
__device__ __forceinline__ float bf_hi(unsigned u) {
  union { unsigned u; float f; } c; c.u = u & 0xffff0000u; return c.f;
}
__device__ __forceinline__ unsigned short f32_bf16(float f) {
  union { float f; unsigned u; } c; c.f = f;
  return (unsigned short)((c.u + 0x7fffu + ((c.u >> 16) & 1u)) >> 16);  // RNE
}
__device__ __forceinline__ unsigned pack_bf16(float a, float b) {
  return (unsigned)f32_bf16(a) | ((unsigned)f32_bf16(b) << 16);
}

__global__ void init_kernel(int* __restrict__ counts, float* __restrict__ stats, int n) {
  int i = blockIdx.x * blockDim.x + threadIdx.x;
  if (i < n) counts[i] = 0;
  if (i < 256) stats[i] = 0.f;
}

// ---- multisplit phase A: per-wave per-partition counts ----
__global__ __launch_bounds__(256) void pcount_kernel(const int* __restrict__ dst,
                                                     int* __restrict__ pcnt,
                                                     int e, int n, int chunk) {
  int w = (int)((blockIdx.x * 256u + threadIdx.x) >> 6);
  int lane = threadIdx.x & 63;
  int beg = w * chunk;
  int end = beg + chunk; if (end > e) end = e;
  int cnt[NPART];
#pragma unroll
  for (int p = 0; p < NPART; ++p) cnt[p] = 0;
  for (int i0 = beg; i0 < end; i0 += 64) {
    int idx = i0 + lane;
    int pe = NPART;
    if (idx < end) {
      int d = __builtin_nontemporal_load(&dst[idx]);
      pe = (int)((8u * (unsigned)d) / (unsigned)n);
    }
#pragma unroll
    for (int p = 0; p < NPART; ++p) cnt[p] += __popcll(__ballot(pe == p));
  }
  if (lane == 0) {
#pragma unroll
    for (int p = 0; p < NPART; ++p) pcnt[p * NW_SPLIT + w] = cnt[p];
  }
}

// ---- multisplit phase C: append (src,dst) int2 to ballot-ranked subranges ----
__global__ __launch_bounds__(256) void ppart_kernel(const int* __restrict__ src,
                                                    const int* __restrict__ dst,
                                                    const int* __restrict__ pscan,
                                                    int2* __restrict__ pedge,
                                                    int e, int n, int chunk) {
  int w = (int)((blockIdx.x * 256u + threadIdx.x) >> 6);
  int lane = threadIdx.x & 63;
  int off[NPART];
#pragma unroll
  for (int p = 0; p < NPART; ++p) off[p] = pscan[p * NW_SPLIT + w];
  int beg = w * chunk;
  int end = beg + chunk; if (end > e) end = e;
  unsigned long long below = ((unsigned long long)1 << lane) - 1ull;
  for (int i0 = beg; i0 < end; i0 += 64) {
    int idx = i0 + lane;
    int s = 0, d = 0, pe = NPART;
    if (idx < end) {
      s = __builtin_nontemporal_load(&src[idx]);
      d = __builtin_nontemporal_load(&dst[idx]);
      pe = (int)((8u * (unsigned)d) / (unsigned)n);
    }
#pragma unroll
    for (int p = 0; p < NPART; ++p) {
      unsigned long long m = __ballot(pe == p);
      int pos = off[p] + __popcll(m & below);
      if (pe == p) pedge[pos] = make_int2(s, d);
      off[p] += __popcll(m);
    }
  }
}

__global__ void dinv_kernel(const int* __restrict__ counts, float* __restrict__ dinv, int n) {
  int i = blockIdx.x * blockDim.x + threadIdx.x;
  if (i < n) dinv[i] = rsqrtf((float)(counts[i] + 1));  // +1 self-loop
}

// ---- hierarchical exclusive scan ----
__global__ __launch_bounds__(1024) void scan1_kernel(const int* __restrict__ counts,
                                                     int* __restrict__ cursor,
                                                     int* __restrict__ bsum, int n) {
  __shared__ int wsum[16];
  int tid = threadIdx.x, lane = tid & 63, wid = tid >> 6;
  int idx = blockIdx.x * 1024 + tid;
  int orig = (idx < n) ? counts[idx] : 0;
  int v = orig;
#pragma unroll
  for (int d = 1; d < 64; d <<= 1) {
    int t = __shfl_up(v, d, 64);
    if (lane >= d) v += t;
  }
  if (lane == 63) wsum[wid] = v;
  __syncthreads();
  if (wid == 0 && lane < 16) {
    int s = wsum[lane];
#pragma unroll
    for (int d = 1; d < 16; d <<= 1) {
      int t = __shfl_up(s, d, 64);
      if (lane >= d) s += t;
    }
    wsum[lane] = s;
  }
  __syncthreads();
  int wexcl = (wid == 0) ? 0 : wsum[wid - 1];
  if (idx < n) cursor[idx] = wexcl + (v - orig);
  if (tid == 0) bsum[blockIdx.x] = wsum[15];
}

__global__ __launch_bounds__(256) void scan2_kernel(const int* __restrict__ bsum,
                                                    int* __restrict__ boff, int nb) {
  __shared__ int wsum[4];
  int tid = threadIdx.x, lane = tid & 63, wid = tid >> 6;
  int orig = (tid < nb) ? bsum[tid] : 0;
  int v = orig;
#pragma unroll
  for (int d = 1; d < 64; d <<= 1) {
    int t = __shfl_up(v, d, 64);
    if (lane >= d) v += t;
  }
  if (lane == 63) wsum[wid] = v;
  __syncthreads();
  if (tid == 0) {
    int run = 0;
#pragma unroll
    for (int w = 0; w < 4; ++w) { int t = wsum[w]; wsum[w] = run; run += t; }
  }
  __syncthreads();
  if (tid < nb) boff[tid] = wsum[wid] + (v - orig);
}

__global__ void scan3_kernel(int* __restrict__ cursor, const int* __restrict__ boff, int n) {
  int i = blockIdx.x * blockDim.x + threadIdx.x;
  if (i < n) cursor[i] += boff[i >> 10];
}

// ---- per-XCD-partition histogram ----
__global__ __launch_bounds__(256) void hist_kernel(const int2* __restrict__ pedge,
                                                   const int* __restrict__ pscan,
                                                   int* __restrict__ counts, int e) {
  int part = blockIdx.x & 7;
  int rank = blockIdx.x >> 3;
  int nrank = gridDim.x >> 3;
  int beg = pscan[part * NW_SPLIT];
  int end = (part < 7) ? pscan[(part + 1) * NW_SPLIT] : e;
  for (int i = beg + rank * 256 + threadIdx.x; i < end; i += nrank * 256)
    atomicAdd(&counts[pedge[i].y], 1);
}

// ---- per-XCD-partition counting-sort scatter ----
__global__ __launch_bounds__(256) void scatter_kernel(const int2* __restrict__ pedge,
                                                      const int* __restrict__ pscan,
                                                      int* __restrict__ cursor,
                                                      int* __restrict__ sorted_src, int e) {
  int part = blockIdx.x & 7;
  int rank = blockIdx.x >> 3;
  int nrank = gridDim.x >> 3;
  int beg = pscan[part * NW_SPLIT];
  int end = (part < 7) ? pscan[(part + 1) * NW_SPLIT] : e;
  for (int i = beg + rank * 256 + threadIdx.x; i < end; i += nrank * 256) {
    int2 sd = pedge[i];
    int pos = atomicAdd(&cursor[sd.y], 1);
    sorted_src[pos] = sd.x;
  }
  // post: cursor[i] == row_end(i); row_beg(i) = cursor[i] - counts[i]
}

// MFMA GEMM + dinv row-scale epilogue: Cb[n][64 words] = bf16(dinv[r] * (A@W)[r][:]).
template <bool ABF16>
__global__ __launch_bounds__(256) void gemm_mfma_kernel(const void* __restrict__ Ap,
                                                        const float* __restrict__ W,
                                                        const float* __restrict__ dinv,
                                                        unsigned* __restrict__ Cb, int n) {
  __shared__ unsigned short WB[16384];  // [kt][ct][nl][q][8 bf16] = 32 KB
  int tid = threadIdx.x;
  for (int idx = tid; idx < 16384; idx += 256) {
    int k = idx >> 7, c = idx & 127;  // W[k][c]
    int kt = k >> 5, q = (k >> 3) & 3, j = k & 7;
    int ct = c >> 4, nl = c & 15;
    WB[(((kt * 8 + ct) * 16 + nl) * 4 + q) * 8 + j] = f32_bf16(W[idx]);
  }
  __syncthreads();
  int lane = tid & 63;
  int m = lane & 15, q = lane >> 4;
  int wv = (int)((blockIdx.x * 256u + tid) >> 6);
  int nwv = (int)((gridDim.x * 256u) >> 6);
  int ntiles = n >> 4;  // n % 16 == 0 here (100000)
  for (int t = wv; t < ntiles; t += nwv) {
    int row = t * 16 + m;
    bf16x8 af[4];
    if (ABF16) {
      const bf16x8* Ar = (const bf16x8*)((const unsigned*)Ap + (size_t)row * 64 + q * 4);
#pragma unroll
      for (int kt = 0; kt < 4; ++kt) af[kt] = Ar[kt * 4];
    } else {
      const float* Arow = (const float*)Ap + (size_t)row * 128 + q * 8;
#pragma unroll
      for (int kt = 0; kt < 4; ++kt) {
        f32x4 a0 = *(const f32x4*)(Arow + kt * 32);
        f32x4 a1 = *(const f32x4*)(Arow + kt * 32 + 4);
        union { bf16x8 v; unsigned short s[8]; } u;
        u.s[0] = f32_bf16(a0.x); u.s[1] = f32_bf16(a0.y);
        u.s[2] = f32_bf16(a0.z); u.s[3] = f32_bf16(a0.w);
        u.s[4] = f32_bf16(a1.x); u.s[5] = f32_bf16(a1.y);
        u.s[6] = f32_bf16(a1.z); u.s[7] = f32_bf16(a1.w);
        af[kt] = u.v;
      }
    }
    f32x4 acc[8];
#pragma unroll
    for (int ct = 0; ct < 8; ++ct) acc[ct] = (f32x4){0.f, 0.f, 0.f, 0.f};
#pragma unroll
    for (int kt = 0; kt < 4; ++kt) {
#pragma unroll
      for (int ct = 0; ct < 8; ++ct) {
        bf16x8 b = *(const bf16x8*)&WB[(((kt * 8 + ct) * 16 + m) * 4 + q) * 8];
        acc[ct] = __builtin_amdgcn_mfma_f32_16x16x32_bf16(af[kt], b, acc[ct], 0, 0, 0);
      }
    }
#pragma unroll
    for (int r4 = 0; r4 < 4; ++r4) {
      int r = t * 16 + q * 4 + r4;
      float dv = dinv[r];  // uniform across the 16 cols being exchanged below
#pragma unroll
      for (int ct = 0; ct < 8; ++ct) {
        float v = acc[ct][r4] * dv;
        float p = __shfl_xor(v, 1, 64);
        if (!(m & 1))
          Cb[(size_t)r * 64 + ct * 8 + (m >> 1)] = pack_bf16(v, p);
      }
    }
  }
}

// agg[i] = dinv[i] * ( sum_e g[src_e] + g[i] ), g pre-scaled by dinv in GEMM.
// Unroll x8: 8 independent row-load chains per wave.
__global__ __launch_bounds__(256) void gather_kernel(const unsigned* __restrict__ g,
    const int* __restrict__ srcs, const int* __restrict__ cursor,
    const int* __restrict__ counts, const float* __restrict__ dinv,
    unsigned* __restrict__ out, int n) {
  int lane = threadIdx.x & 63;
  int gw = (int)((blockIdx.x * blockDim.x + threadIdx.x) >> 6);
  int nw = (int)((gridDim.x * blockDim.x) >> 6);
  for (int i0 = gw; i0 < n; i0 += nw) {
    int i = __builtin_amdgcn_readfirstlane(i0);
    int end = cursor[i];
    int cnt = counts[i];
    int beg = end - cnt;
    float di = dinv[i];
    unsigned hv = g[(size_t)i * 64 + lane];
    float ax0 = bf_lo(hv), ay0 = bf_hi(hv);  // self-loop term g[i]
    float ax1 = 0.f, ay1 = 0.f;
    int e = beg;
    for (; e + 8 <= end; e += 8) {
      int s0 = srcs[e + 0], s1 = srcs[e + 1], s2 = srcs[e + 2], s3 = srcs[e + 3];
      int s4 = srcs[e + 4], s5 = srcs[e + 5], s6 = srcs[e + 6], s7 = srcs[e + 7];
      unsigned v0 = g[(size_t)s0 * 64 + lane];
      unsigned v1 = g[(size_t)s1 * 64 + lane];
      unsigned v2 = g[(size_t)s2 * 64 + lane];
      unsigned v3 = g[(size_t)s3 * 64 + lane];
      unsigned v4 = g[(size_t)s4 * 64 + lane];
      unsigned v5 = g[(size_t)s5 * 64 + lane];
      unsigned v6 = g[(size_t)s6 * 64 + lane];
      unsigned v7 = g[(size_t)s7 * 64 + lane];
      ax0 += bf_lo(v0); ay0 += bf_hi(v0);
      ax1 += bf_lo(v1); ay1 += bf_hi(v1);
      ax0 += bf_lo(v2); ay0 += bf_hi(v2);
      ax1 += bf_lo(v3); ay1 += bf_hi(v3);
      ax0 += bf_lo(v4); ay0 += bf_hi(v4);
      ax1 += bf_lo(v5); ay1 += bf_hi(v5);
      ax0 += bf_lo(v6); ay0 += bf_hi(v6);
      ax1 += bf_lo(v7); ay1 += bf_hi(v7);
    }
    for (; e + 4 <= end; e += 4) {
      int s0 = srcs[e + 0], s1 = srcs[e + 1], s2 = srcs[e + 2], s3 = srcs[e + 3];
      unsigned v0 = g[(size_t)s0 * 64 + lane];
      unsigned v1 = g[(size_t)s1 * 64 + lane];
      unsigned v2 = g[(size_t)s2 * 64 + lane];
      unsigned v3 = g[(size_t)s3 * 64 + lane];
      ax0 += bf_lo(v0); ay0 += bf_hi(v0);
      ax1 += bf_lo(v1); ay1 += bf_hi(v1);
      ax0 += bf_lo(v2); ay0 += bf_hi(v2);
      ax1 += bf_lo(v3); ay1 += bf_hi(v3);
    }
    for (; e < end; ++e) {
      int s = srcs[e];
      unsigned v = g[(size_t)s * 64 + lane];
      ax0 += bf_lo(v); ay0 += bf_hi(v);
    }
    out[(size_t)i * 64 + lane] = pack_bf16(di * (ax0 + ax1), di * (ay0 + ay1));
  }
}

__global__ __launch_bounds__(256) void bn_stats_kernel(const unsigned* __restrict__ a,
                                                       float* __restrict__ stats, int n) {
  int c2 = threadIdx.x & 63;
  int ph = threadIdx.x >> 6;
  float s0 = 0.f, s1 = 0.f, q0 = 0.f, q1 = 0.f;
  for (int r = blockIdx.x * 4 + ph; r < n; r += gridDim.x * 4) {
    unsigned v = a[(size_t)r * 64 + c2];
    float x0 = bf_lo(v), x1 = bf_hi(v);
    s0 += x0; s1 += x1; q0 += x0 * x0; q1 += x1 * x1;
  }
  __shared__ float ls[4][64][4];
  ls[ph][c2][0] = s0; ls[ph][c2][1] = s1; ls[ph][c2][2] = q0; ls[ph][c2][3] = q1;
  __syncthreads();
  if (threadIdx.x < 64) {
    int c = threadIdx.x;
    float S0 = 0.f, S1 = 0.f, Q0 = 0.f, Q1 = 0.f;
#pragma unroll
    for (int p = 0; p < 4; ++p) {
      S0 += ls[p][c][0]; S1 += ls[p][c][1]; Q0 += ls[p][c][2]; Q1 += ls[p][c][3];
    }
    atomicAdd(&stats[2 * c], S0);
    atomicAdd(&stats[2 * c + 1], S1);
    atomicAdd(&stats[128 + 2 * c], Q0);
    atomicAdd(&stats[129 + 2 * c], Q1);
  }
}

// In-place y = bf16(relu(gamma*(a-mu)*rstd + beta)); packed.
__global__ __launch_bounds__(256) void bn_relu_kernel(unsigned* __restrict__ a,
    const float* __restrict__ stats, const float* __restrict__ gamma,
    const float* __restrict__ beta, int n) {
  __shared__ float sc[128], sh[128];
  int tid = threadIdx.x;
  if (tid < 128) {
    float invN = 1.f / (float)n;
    float mu = stats[tid] * invN;
    float var = stats[128 + tid] * invN - mu * mu;
    float rstd = rsqrtf(var + 1e-5f);
    float s = gamma[tid] * rstd;
    sc[tid] = s;
    sh[tid] = beta[tid] - mu * s;
  }
  __syncthreads();
  size_t total = (size_t)n * 64;
  for (size_t w = blockIdx.x * (size_t)blockDim.x + tid; w < total;
       w += (size_t)gridDim.x * blockDim.x) {
    int c2 = (int)(w & 63);
    unsigned v = a[w];
    float y0 = fmaxf(fmaf(sc[2 * c2], bf_lo(v), sh[2 * c2]), 0.f);
    float y1 = fmaxf(fmaf(sc[2 * c2 + 1], bf_hi(v), sh[2 * c2 + 1]), 0.f);
    a[w] = pack_bf16(y0, y1);
  }
}

__global__ void gstart_kernel(const int* __restrict__ batch, int* __restrict__ gstart,
                              int n, int G) {
  int g = blockIdx.x * blockDim.x + threadIdx.x;
  if (g > G) return;
  if (g == G) { gstart[g] = n; return; }
  int lo = 0, hi = n;
  while (lo < hi) {
    int mid = (lo + hi) >> 1;
    if (batch[mid] < g) lo = mid + 1; else hi = mid;
  }
  gstart[g] = lo;
}

__global__ __launch_bounds__(256) void pool_kernel(const unsigned* __restrict__ a,
    const int* __restrict__ gstart, const float* __restrict__ b2,
    float* __restrict__ pooled, int G) {
  int g = blockIdx.x;
  int c2 = threadIdx.x & 63;
  int ph = threadIdx.x >> 6;
  int s = gstart[g], e = gstart[g + 1];
  float a0 = 0.f, a1 = 0.f;
  for (int r = s + ph; r < e; r += 4) {
    unsigned v = a[(size_t)r * 64 + c2];
    a0 += bf_lo(v); a1 += bf_hi(v);
  }
  __shared__ float ls[4][64][2];
  ls[ph][c2][0] = a0; ls[ph][c2][1] = a1;
  __syncthreads();
  if (threadIdx.x < 64) {
    int c = threadIdx.x;
    float S0 = 0.f, S1 = 0.f;
#pragma unroll
    for (int p = 0; p < 4; ++p) { S0 += ls[p][c][0]; S1 += ls[p][c][1]; }
    int cnt = e - s;
    float inv = (cnt > 0) ? 1.f / (float)cnt : 0.f;
    float2 res;
    res.x = (cnt > 0) ? (S0 * inv + b2[2 * c]) : 0.f;
    res.y = (cnt > 0) ? (S1 * inv + b2[2 * c + 1]) : 0.f;
    ((float2*)(pooled + (size_t)g * 128))[c] = res;
  }
}

__global__ __launch_bounds__(128) void head_kernel(const float* __restrict__ pooled,
    const float* __restrict__ rst, const float* __restrict__ Wg, const float* __restrict__ bg,
    const float* __restrict__ Wr, const float* __restrict__ br, const float* __restrict__ Wc,
    const float* __restrict__ bc, float* __restrict__ out, int G) {
  int g = blockIdx.x;
  int t = threadIdx.x;
  __shared__ float xc[128];
  if (t < 64) {
    float acc = bg[t];
    const float* __restrict__ p = pooled + (size_t)g * 128;
    for (int k = 0; k < 128; ++k) acc = fmaf(p[k], Wg[k * 64 + t], acc);
    xc[t] = fmaxf(acc, 0.f);
  } else {
    int j = t - 64;
    float acc = br[j];
    const float* __restrict__ r = rst + (size_t)g * 64;
    for (int k = 0; k < 64; ++k) acc = fmaf(r[k], Wr[k * 64 + j], acc);
    xc[t] = fmaxf(acc, 0.f);
  }
  __syncthreads();
  if (t < 2) {
    float acc = bc[t];
    for (int j = 0; j < 128; ++j) acc = fmaf(xc[j], Wc[j * 2 + t], acc);
    out[(size_t)g * 2 + t] = acc;
  }
}

extern "C" void kernel_launch(void* const* d_in, const int* in_sizes, int n_in,
                              void* d_out, int out_size, void* d_ws, size_t ws_size,
                              hipStream_t stream) {
  (void)n_in; (void)ws_size;
  const float* x     = (const float*)d_in[0];
  const int*   ei    = (const int*)d_in[1];
  const int*   batch = (const int*)d_in[2];
  const float* rst   = (const float*)d_in[3];
  const float* W1    = (const float*)d_in[5];
  // d_in[6] = b1 — cancels in BatchNorm, skipped
  const float* gamma = (const float*)d_in[7];
  const float* beta  = (const float*)d_in[8];
  const float* W2    = (const float*)d_in[9];
  const float* b2    = (const float*)d_in[10];
  const float* Wg    = (const float*)d_in[11];
  const float* bg    = (const float*)d_in[12];
  const float* Wr    = (const float*)d_in[13];
  const float* br    = (const float*)d_in[14];
  const float* Wc    = (const float*)d_in[15];
  const float* bc    = (const float*)d_in[16];
  float* out = (float*)d_out;

  int N = in_sizes[0] / 128;
  int E = in_sizes[1] / 2;
  int G = out_size / 2;
  const int* esrc = ei;
  const int* edst = ei + E;

  char* ws = (char*)d_ws;
  size_t off = 0;
  auto alloc = [&](size_t bytes) -> void* {
    void* p = ws + off;
    off += (bytes + 255) & ~(size_t)255;
    return p;
  };
  unsigned* hb  = (unsigned*)alloc((size_t)N * 64 * 4);  // packed bf16 g1/g2
  unsigned* agb = (unsigned*)alloc((size_t)N * 64 * 4);  // agg1b -> y1 (in place) -> agg2b
  int* sorted   = (int*)alloc((size_t)E * 4);
  int2* pedge   = (int2*)alloc((size_t)E * 8);           // partitioned (src,dst)
  int* pcnt     = (int*)alloc((size_t)NPART * NW_SPLIT * 4);
  int* pscan    = (int*)alloc((size_t)NPART * NW_SPLIT * 4);
  int* counts   = (int*)alloc((size_t)N * 4);
  int* cursor   = (int*)alloc((size_t)N * 4);
  float* dinv   = (float*)alloc((size_t)N * 4);
  float* stats  = (float*)alloc(256 * 4);
  int* gstart   = (int*)alloc((size_t)(G + 1) * 4);
  float* pooled = (float*)alloc((size_t)G * 128 * 4);
  int* bsum     = (int*)alloc(256 * 4);
  int* boff     = (int*)alloc(256 * 4);
  int* pbsum    = (int*)alloc(256 * 4);
  int* pboff    = (int*)alloc(256 * 4);

  int nb = (N + 255) / 256;
  int nscan = (N + 1023) / 1024;
  int chunk = (E + NW_SPLIT - 1) / NW_SPLIT;
  int npsc = (NPART * NW_SPLIT) / 1024;  // 32

  init_kernel<<<nb, 256, 0, stream>>>(counts, stats, N);
  pcount_kernel<<<NW_SPLIT / 4, 256, 0, stream>>>(edst, pcnt, E, N, chunk);
  scan1_kernel<<<npsc, 1024, 0, stream>>>(pcnt, pscan, pbsum, NPART * NW_SPLIT);
  scan2_kernel<<<1, 256, 0, stream>>>(pbsum, pboff, npsc);
  scan3_kernel<<<(NPART * NW_SPLIT) / 256, 256, 0, stream>>>(pscan, pboff, NPART * NW_SPLIT);
  ppart_kernel<<<NW_SPLIT / 4, 256, 0, stream>>>(esrc, edst, pscan, pedge, E, N, chunk);
  hist_kernel<<<2048, 256, 0, stream>>>(pedge, pscan, counts, E);
  dinv_kernel<<<nb, 256, 0, stream>>>(counts, dinv, N);
  scan1_kernel<<<nscan, 1024, 0, stream>>>(counts, cursor, bsum, N);
  scan2_kernel<<<1, 256, 0, stream>>>(bsum, boff, nscan);
  scan3_kernel<<<(N + 255) / 256, 256, 0, stream>>>(cursor, boff, N);
  scatter_kernel<<<2048, 256, 0, stream>>>(pedge, pscan, cursor, sorted, E);

  gemm_mfma_kernel<false><<<1024, 256, 0, stream>>>(x, W1, dinv, hb, N);
  gather_kernel<<<4096, 256, 0, stream>>>(hb, sorted, cursor, counts, dinv, agb, N);

  bn_stats_kernel<<<512, 256, 0, stream>>>(agb, stats, N);
  bn_relu_kernel<<<2048, 256, 0, stream>>>(agb, stats, gamma, beta, N);

  gemm_mfma_kernel<true><<<1024, 256, 0, stream>>>(agb, W2, dinv, hb, N);
  gather_kernel<<<4096, 256, 0, stream>>>(hb, sorted, cursor, counts, dinv, agb, N);

  gstart_kernel<<<(G + 1 + 255) / 256, 256, 0, stream>>>(batch, gstart, N, G);
  pool_kernel<<<G, 256, 0, stream>>>(agb, gstart, b2, pooled, G);
  head_kernel<<<G, 128, 0, stream>>>(pooled, rst, Wg, bg, Wr, br, Wc, bc, out, G);
}

// Round 7
// 444.135 us; speedup vs baseline: 1.2834x; 1.2413x over previous
//
#include <hip/hip_runtime.h>

// Pipeline (node features packed bf16 pairs; word c = channels 2c,2c+1):
//  init -> tile_hist -> scan(tcnt) -> tile_scatter (radix pass: edges bucket-
//  grouped by dst>>9, ALL stores coalesced) -> deg_count (LDS hist per bucket)
//  -> dinv -> scan(counts) -> bucket_sort (LDS counting sort per 512-node
//  bucket, sequential writes -> sorted[] CSR; cursor stays row-starts)
//  -> gemm_mfma<f32 A> (g1 = dinv .* bf16(x@W1); b1 cancels in BN)
//  -> gather (agg1b = di*(sum g1[src] + g1[i]))
//  -> bn_stats -> bn_relu (in place)
//  -> gemm_mfma<bf16 A> (g2) -> gather (agg2b)
//  -> gstart -> pool (+b2) -> head
//
// HW law (R1/R4/R6 measured): scattered dword stores cost ~40-64B HBM
// writeback each; L2 never assembles them. Hence: every global store in the
// sort pipeline below is sequential/coalesced.

typedef __attribute__((ext_vector_type(8))) short bf16x8;
typedef __attribute__((ext_vector_type(4))) float f32x4;

#define NBKT_MAX 256
#define BKT_SHIFT 9            // bucket = dst >> 9 (512 nodes per bucket)
#define TILE_E 4000            // edges per radix tile
#define BSORT_CAP 12544        // LDS staging cap per bucket (~mean 8192 + 48 sigma)

__device__ __forceinline__ float bf_lo(unsigned u) {
  union { unsigned u; float f; } c; c.u = u << 16; return c.f;
}
__device__ __forceinline__ float bf_hi(unsigned u) {
  union { unsigned u; float f; } c; c.u = u & 0xffff0000u; return c.f;
}
__device__ __forceinline__ unsigned short f32_bf16(float f) {
  union { float f; unsigned u; } c; c.f = f;
  return (unsigned short)((c.u + 0x7fffu + ((c.u >> 16) & 1u)) >> 16);  // RNE
}
__device__ __forceinline__ unsigned pack_bf16(float a, float b) {
  return (unsigned)f32_bf16(a) | ((unsigned)f32_bf16(b) << 16);
}

__global__ void init_kernel(float* __restrict__ stats) {
  int i = blockIdx.x * blockDim.x + threadIdx.x;
  if (i < 256) stats[i] = 0.f;
}

// ---- radix pass A: per-tile bucket histogram ----
__global__ __launch_bounds__(256) void tile_hist_kernel(const int* __restrict__ dst,
                                                        int* __restrict__ tcnt,
                                                        int e, int ntiles, int nbkt) {
  __shared__ int hist[NBKT_MAX];
  int tile = blockIdx.x;
  for (int b = threadIdx.x; b < nbkt; b += 256) hist[b] = 0;
  __syncthreads();
  int t0 = tile * TILE_E;
  int tend = t0 + TILE_E; if (tend > e) tend = e;
  for (int i = t0 + threadIdx.x; i < tend; i += 256)
    atomicAdd(&hist[__builtin_nontemporal_load(&dst[i]) >> BKT_SHIFT], 1);
  __syncthreads();
  for (int b = threadIdx.x; b < nbkt; b += 256) tcnt[b * ntiles + tile] = hist[b];
}

// ---- radix pass A scatter: LDS-staged bucket grouping, coalesced writes ----
__global__ __launch_bounds__(256) void tile_scatter_kernel(const int* __restrict__ src,
                                                           const int* __restrict__ dst,
                                                           const int* __restrict__ toff,
                                                           int2* __restrict__ pedge,
                                                           int e, int ntiles, int nbkt) {
  __shared__ int hist[NBKT_MAX], cnt[NBKT_MAX], gbase[NBKT_MAX];
  __shared__ int2 led[TILE_E];
  int tile = blockIdx.x;
  for (int b = threadIdx.x; b < nbkt; b += 256) { hist[b] = 0; cnt[b] = 0; }
  __syncthreads();
  int t0 = tile * TILE_E;
  int tend = t0 + TILE_E; if (tend > e) tend = e;
  for (int i = t0 + threadIdx.x; i < tend; i += 256)
    atomicAdd(&hist[__builtin_nontemporal_load(&dst[i]) >> BKT_SHIFT], 1);
  __syncthreads();
  if (threadIdx.x == 0) {  // exclusive scan hist in place (196 adds, negligible)
    int run = 0;
    for (int b = 0; b < nbkt; ++b) { int t = hist[b]; hist[b] = run; run += t; }
  }
  for (int b = threadIdx.x; b < nbkt; b += 256) gbase[b] = toff[b * ntiles + tile];
  __syncthreads();
  for (int i = t0 + threadIdx.x; i < tend; i += 256) {
    int s = __builtin_nontemporal_load(&src[i]);
    int d = __builtin_nontemporal_load(&dst[i]);
    int bkt = d >> BKT_SHIFT;
    int slot = hist[bkt] + atomicAdd(&cnt[bkt], 1);
    led[slot] = make_int2(s, d);
  }
  __syncthreads();
  int tcount = tend - t0;
  for (int j = threadIdx.x; j < tcount; j += 256) {
    int2 sd = led[j];
    int bkt = sd.y >> BKT_SHIFT;
    pedge[gbase[bkt] + (j - hist[bkt])] = sd;  // runs of ~20 int2 -> full lines
  }
}

// ---- per-bucket degree count via LDS histogram (replaces global hist atomics) ----
__global__ __launch_bounds__(256) void deg_count_kernel(const int2* __restrict__ pedge,
                                                        const int* __restrict__ toff,
                                                        int* __restrict__ counts,
                                                        int e, int ntiles, int nbkt, int n) {
  __shared__ int cnt[512];
  int b = blockIdx.x;
  int nb0 = b << BKT_SHIFT;
  int nn = n - nb0; if (nn > 512) nn = 512;
  for (int l = threadIdx.x; l < 512; l += 256) cnt[l] = 0;
  __syncthreads();
  int estart = toff[b * ntiles];
  int eend = (b + 1 < nbkt) ? toff[(b + 1) * ntiles] : e;
  for (int i = estart + threadIdx.x; i < eend; i += 256)
    atomicAdd(&cnt[pedge[i].y - nb0], 1);
  __syncthreads();
  for (int l = threadIdx.x; l < nn; l += 256) counts[nb0 + l] = cnt[l];
}

__global__ void dinv_kernel(const int* __restrict__ counts, float* __restrict__ dinv, int n) {
  int i = blockIdx.x * blockDim.x + threadIdx.x;
  if (i < n) dinv[i] = rsqrtf((float)(counts[i] + 1));  // +1 self-loop
}

// ---- hierarchical exclusive scan ----
__global__ __launch_bounds__(1024) void scan1_kernel(const int* __restrict__ counts,
                                                     int* __restrict__ cursor,
                                                     int* __restrict__ bsum, int n) {
  __shared__ int wsum[16];
  int tid = threadIdx.x, lane = tid & 63, wid = tid >> 6;
  int idx = blockIdx.x * 1024 + tid;
  int orig = (idx < n) ? counts[idx] : 0;
  int v = orig;
#pragma unroll
  for (int d = 1; d < 64; d <<= 1) {
    int t = __shfl_up(v, d, 64);
    if (lane >= d) v += t;
  }
  if (lane == 63) wsum[wid] = v;
  __syncthreads();
  if (wid == 0 && lane < 16) {
    int s = wsum[lane];
#pragma unroll
    for (int d = 1; d < 16; d <<= 1) {
      int t = __shfl_up(s, d, 64);
      if (lane >= d) s += t;
    }
    wsum[lane] = s;
  }
  __syncthreads();
  int wexcl = (wid == 0) ? 0 : wsum[wid - 1];
  if (idx < n) cursor[idx] = wexcl + (v - orig);
  if (tid == 0) bsum[blockIdx.x] = wsum[15];
}

__global__ __launch_bounds__(256) void scan2_kernel(const int* __restrict__ bsum,
                                                    int* __restrict__ boff, int nb) {
  __shared__ int wsum[4];
  int tid = threadIdx.x, lane = tid & 63, wid = tid >> 6;
  int orig = (tid < nb) ? bsum[tid] : 0;
  int v = orig;
#pragma unroll
  for (int d = 1; d < 64; d <<= 1) {
    int t = __shfl_up(v, d, 64);
    if (lane >= d) v += t;
  }
  if (lane == 63) wsum[wid] = v;
  __syncthreads();
  if (tid == 0) {
    int run = 0;
#pragma unroll
    for (int w = 0; w < 4; ++w) { int t = wsum[w]; wsum[w] = run; run += t; }
  }
  __syncthreads();
  if (tid < nb) boff[tid] = wsum[wid] + (v - orig);
}

__global__ void scan3_kernel(int* __restrict__ cursor, const int* __restrict__ boff, int n) {
  int i = blockIdx.x * blockDim.x + threadIdx.x;
  if (i < n) cursor[i] += boff[i >> 10];
}

// ---- final exact counting sort per 512-node bucket, all-sequential writes ----
__global__ __launch_bounds__(256) void bucket_sort_kernel(const int2* __restrict__ pedge,
                                                          const int* __restrict__ toff,
                                                          const int* __restrict__ cursor,
                                                          int* __restrict__ sorted_src,
                                                          int e, int ntiles, int nbkt, int n) {
  __shared__ int lcur[512];
  __shared__ int lsrc[BSORT_CAP];
  int b = blockIdx.x;
  int nb0 = b << BKT_SHIFT;
  int nn = n - nb0; if (nn > 512) nn = 512;
  int estart = toff[b * ntiles];
  int eend = (b + 1 < nbkt) ? toff[(b + 1) * ntiles] : e;
  for (int l = threadIdx.x; l < nn; l += 256) lcur[l] = cursor[nb0 + l] - estart;
  __syncthreads();
  for (int i = estart + threadIdx.x; i < eend; i += 256) {
    int2 sd = pedge[i];
    int pos = atomicAdd(&lcur[sd.y - nb0], 1);
    if (pos < BSORT_CAP) lsrc[pos] = sd.x;
  }
  __syncthreads();
  int cnt = eend - estart;
  if (cnt > BSORT_CAP) cnt = BSORT_CAP;
  for (int j = threadIdx.x; j < cnt; j += 256) sorted_src[estart + j] = lsrc[j];
}

// MFMA GEMM + dinv row-scale epilogue: Cb[n][64 words] = bf16(dinv[r] * (A@W)[r][:]).
template <bool ABF16>
__global__ __launch_bounds__(256) void gemm_mfma_kernel(const void* __restrict__ Ap,
                                                        const float* __restrict__ W,
                                                        const float* __restrict__ dinv,
                                                        unsigned* __restrict__ Cb, int n) {
  __shared__ unsigned short WB[16384];  // [kt][ct][nl][q][8 bf16] = 32 KB
  int tid = threadIdx.x;
  for (int idx = tid; idx < 16384; idx += 256) {
    int k = idx >> 7, c = idx & 127;  // W[k][c]
    int kt = k >> 5, q = (k >> 3) & 3, j = k & 7;
    int ct = c >> 4, nl = c & 15;
    WB[(((kt * 8 + ct) * 16 + nl) * 4 + q) * 8 + j] = f32_bf16(W[idx]);
  }
  __syncthreads();
  int lane = tid & 63;
  int m = lane & 15, q = lane >> 4;
  int wv = (int)((blockIdx.x * 256u + tid) >> 6);
  int nwv = (int)((gridDim.x * 256u) >> 6);
  int ntiles = n >> 4;  // n % 16 == 0 here (100000)
  for (int t = wv; t < ntiles; t += nwv) {
    int row = t * 16 + m;
    bf16x8 af[4];
    if (ABF16) {
      const bf16x8* Ar = (const bf16x8*)((const unsigned*)Ap + (size_t)row * 64 + q * 4);
#pragma unroll
      for (int kt = 0; kt < 4; ++kt) af[kt] = Ar[kt * 4];
    } else {
      const float* Arow = (const float*)Ap + (size_t)row * 128 + q * 8;
#pragma unroll
      for (int kt = 0; kt < 4; ++kt) {
        f32x4 a0 = *(const f32x4*)(Arow + kt * 32);
        f32x4 a1 = *(const f32x4*)(Arow + kt * 32 + 4);
        union { bf16x8 v; unsigned short s[8]; } u;
        u.s[0] = f32_bf16(a0.x); u.s[1] = f32_bf16(a0.y);
        u.s[2] = f32_bf16(a0.z); u.s[3] = f32_bf16(a0.w);
        u.s[4] = f32_bf16(a1.x); u.s[5] = f32_bf16(a1.y);
        u.s[6] = f32_bf16(a1.z); u.s[7] = f32_bf16(a1.w);
        af[kt] = u.v;
      }
    }
    f32x4 acc[8];
#pragma unroll
    for (int ct = 0; ct < 8; ++ct) acc[ct] = (f32x4){0.f, 0.f, 0.f, 0.f};
#pragma unroll
    for (int kt = 0; kt < 4; ++kt) {
#pragma unroll
      for (int ct = 0; ct < 8; ++ct) {
        bf16x8 b = *(const bf16x8*)&WB[(((kt * 8 + ct) * 16 + m) * 4 + q) * 8];
        acc[ct] = __builtin_amdgcn_mfma_f32_16x16x32_bf16(af[kt], b, acc[ct], 0, 0, 0);
      }
    }
#pragma unroll
    for (int r4 = 0; r4 < 4; ++r4) {
      int r = t * 16 + q * 4 + r4;
      float dv = dinv[r];
#pragma unroll
      for (int ct = 0; ct < 8; ++ct) {
        float v = acc[ct][r4] * dv;
        float p = __shfl_xor(v, 1, 64);
        if (!(m & 1))
          Cb[(size_t)r * 64 + ct * 8 + (m >> 1)] = pack_bf16(v, p);
      }
    }
  }
}

// agg[i] = dinv[i] * ( sum_e g[src_e] + g[i] ), g pre-scaled by dinv in GEMM.
// cursor = row starts (pristine); end = beg + counts[i]. Unroll x8 for MLP.
__global__ __launch_bounds__(256) void gather_kernel(const unsigned* __restrict__ g,
    const int* __restrict__ srcs, const int* __restrict__ cursor,
    const int* __restrict__ counts, const float* __restrict__ dinv,
    unsigned* __restrict__ out, int n) {
  int lane = threadIdx.x & 63;
  int gw = (int)((blockIdx.x * blockDim.x + threadIdx.x) >> 6);
  int nw = (int)((gridDim.x * blockDim.x) >> 6);
  for (int i0 = gw; i0 < n; i0 += nw) {
    int i = __builtin_amdgcn_readfirstlane(i0);
    int beg = cursor[i];
    int cnt = counts[i];
    int end = beg + cnt;
    float di = dinv[i];
    unsigned hv = g[(size_t)i * 64 + lane];
    float ax0 = bf_lo(hv), ay0 = bf_hi(hv);  // self-loop term g[i]
    float ax1 = 0.f, ay1 = 0.f;
    int e = beg;
    for (; e + 8 <= end; e += 8) {
      int s0 = srcs[e + 0], s1 = srcs[e + 1], s2 = srcs[e + 2], s3 = srcs[e + 3];
      int s4 = srcs[e + 4], s5 = srcs[e + 5], s6 = srcs[e + 6], s7 = srcs[e + 7];
      unsigned v0 = g[(size_t)s0 * 64 + lane];
      unsigned v1 = g[(size_t)s1 * 64 + lane];
      unsigned v2 = g[(size_t)s2 * 64 + lane];
      unsigned v3 = g[(size_t)s3 * 64 + lane];
      unsigned v4 = g[(size_t)s4 * 64 + lane];
      unsigned v5 = g[(size_t)s5 * 64 + lane];
      unsigned v6 = g[(size_t)s6 * 64 + lane];
      unsigned v7 = g[(size_t)s7 * 64 + lane];
      ax0 += bf_lo(v0); ay0 += bf_hi(v0);
      ax1 += bf_lo(v1); ay1 += bf_hi(v1);
      ax0 += bf_lo(v2); ay0 += bf_hi(v2);
      ax1 += bf_lo(v3); ay1 += bf_hi(v3);
      ax0 += bf_lo(v4); ay0 += bf_hi(v4);
      ax1 += bf_lo(v5); ay1 += bf_hi(v5);
      ax0 += bf_lo(v6); ay0 += bf_hi(v6);
      ax1 += bf_lo(v7); ay1 += bf_hi(v7);
    }
    for (; e + 4 <= end; e += 4) {
      int s0 = srcs[e + 0], s1 = srcs[e + 1], s2 = srcs[e + 2], s3 = srcs[e + 3];
      unsigned v0 = g[(size_t)s0 * 64 + lane];
      unsigned v1 = g[(size_t)s1 * 64 + lane];
      unsigned v2 = g[(size_t)s2 * 64 + lane];
      unsigned v3 = g[(size_t)s3 * 64 + lane];
      ax0 += bf_lo(v0); ay0 += bf_hi(v0);
      ax1 += bf_lo(v1); ay1 += bf_hi(v1);
      ax0 += bf_lo(v2); ay0 += bf_hi(v2);
      ax1 += bf_lo(v3); ay1 += bf_hi(v3);
    }
    for (; e < end; ++e) {
      int s = srcs[e];
      unsigned v = g[(size_t)s * 64 + lane];
      ax0 += bf_lo(v); ay0 += bf_hi(v);
    }
    out[(size_t)i * 64 + lane] = pack_bf16(di * (ax0 + ax1), di * (ay0 + ay1));
  }
}

__global__ __launch_bounds__(256) void bn_stats_kernel(const unsigned* __restrict__ a,
                                                       float* __restrict__ stats, int n) {
  int c2 = threadIdx.x & 63;
  int ph = threadIdx.x >> 6;
  float s0 = 0.f, s1 = 0.f, q0 = 0.f, q1 = 0.f;
  for (int r = blockIdx.x * 4 + ph; r < n; r += gridDim.x * 4) {
    unsigned v = a[(size_t)r * 64 + c2];
    float x0 = bf_lo(v), x1 = bf_hi(v);
    s0 += x0; s1 += x1; q0 += x0 * x0; q1 += x1 * x1;
  }
  __shared__ float ls[4][64][4];
  ls[ph][c2][0] = s0; ls[ph][c2][1] = s1; ls[ph][c2][2] = q0; ls[ph][c2][3] = q1;
  __syncthreads();
  if (threadIdx.x < 64) {
    int c = threadIdx.x;
    float S0 = 0.f, S1 = 0.f, Q0 = 0.f, Q1 = 0.f;
#pragma unroll
    for (int p = 0; p < 4; ++p) {
      S0 += ls[p][c][0]; S1 += ls[p][c][1]; Q0 += ls[p][c][2]; Q1 += ls[p][c][3];
    }
    atomicAdd(&stats[2 * c], S0);
    atomicAdd(&stats[2 * c + 1], S1);
    atomicAdd(&stats[128 + 2 * c], Q0);
    atomicAdd(&stats[129 + 2 * c], Q1);
  }
}

// In-place y = bf16(relu(gamma*(a-mu)*rstd + beta)); packed.
__global__ __launch_bounds__(256) void bn_relu_kernel(unsigned* __restrict__ a,
    const float* __restrict__ stats, const float* __restrict__ gamma,
    const float* __restrict__ beta, int n) {
  __shared__ float sc[128], sh[128];
  int tid = threadIdx.x;
  if (tid < 128) {
    float invN = 1.f / (float)n;
    float mu = stats[tid] * invN;
    float var = stats[128 + tid] * invN - mu * mu;
    float rstd = rsqrtf(var + 1e-5f);
    float s = gamma[tid] * rstd;
    sc[tid] = s;
    sh[tid] = beta[tid] - mu * s;
  }
  __syncthreads();
  size_t total = (size_t)n * 64;
  for (size_t w = blockIdx.x * (size_t)blockDim.x + tid; w < total;
       w += (size_t)gridDim.x * blockDim.x) {
    int c2 = (int)(w & 63);
    unsigned v = a[w];
    float y0 = fmaxf(fmaf(sc[2 * c2], bf_lo(v), sh[2 * c2]), 0.f);
    float y1 = fmaxf(fmaf(sc[2 * c2 + 1], bf_hi(v), sh[2 * c2 + 1]), 0.f);
    a[w] = pack_bf16(y0, y1);
  }
}

__global__ void gstart_kernel(const int* __restrict__ batch, int* __restrict__ gstart,
                              int n, int G) {
  int g = blockIdx.x * blockDim.x + threadIdx.x;
  if (g > G) return;
  if (g == G) { gstart[g] = n; return; }
  int lo = 0, hi = n;
  while (lo < hi) {
    int mid = (lo + hi) >> 1;
    if (batch[mid] < g) lo = mid + 1; else hi = mid;
  }
  gstart[g] = lo;
}

__global__ __launch_bounds__(256) void pool_kernel(const unsigned* __restrict__ a,
    const int* __restrict__ gstart, const float* __restrict__ b2,
    float* __restrict__ pooled, int G) {
  int g = blockIdx.x;
  int c2 = threadIdx.x & 63;
  int ph = threadIdx.x >> 6;
  int s = gstart[g], e = gstart[g + 1];
  float a0 = 0.f, a1 = 0.f;
  for (int r = s + ph; r < e; r += 4) {
    unsigned v = a[(size_t)r * 64 + c2];
    a0 += bf_lo(v); a1 += bf_hi(v);
  }
  __shared__ float ls[4][64][2];
  ls[ph][c2][0] = a0; ls[ph][c2][1] = a1;
  __syncthreads();
  if (threadIdx.x < 64) {
    int c = threadIdx.x;
    float S0 = 0.f, S1 = 0.f;
#pragma unroll
    for (int p = 0; p < 4; ++p) { S0 += ls[p][c][0]; S1 += ls[p][c][1]; }
    int cnt = e - s;
    float inv = (cnt > 0) ? 1.f / (float)cnt : 0.f;
    float2 res;
    res.x = (cnt > 0) ? (S0 * inv + b2[2 * c]) : 0.f;
    res.y = (cnt > 0) ? (S1 * inv + b2[2 * c + 1]) : 0.f;
    ((float2*)(pooled + (size_t)g * 128))[c] = res;
  }
}

__global__ __launch_bounds__(128) void head_kernel(const float* __restrict__ pooled,
    const float* __restrict__ rst, const float* __restrict__ Wg, const float* __restrict__ bg,
    const float* __restrict__ Wr, const float* __restrict__ br, const float* __restrict__ Wc,
    const float* __restrict__ bc, float* __restrict__ out, int G) {
  int g = blockIdx.x;
  int t = threadIdx.x;
  __shared__ float xc[128];
  if (t < 64) {
    float acc = bg[t];
    const float* __restrict__ p = pooled + (size_t)g * 128;
    for (int k = 0; k < 128; ++k) acc = fmaf(p[k], Wg[k * 64 + t], acc);
    xc[t] = fmaxf(acc, 0.f);
  } else {
    int j = t - 64;
    float acc = br[j];
    const float* __restrict__ r = rst + (size_t)g * 64;
    for (int k = 0; k < 64; ++k) acc = fmaf(r[k], Wr[k * 64 + j], acc);
    xc[t] = fmaxf(acc, 0.f);
  }
  __syncthreads();
  if (t < 2) {
    float acc = bc[t];
    for (int j = 0; j < 128; ++j) acc = fmaf(xc[j], Wc[j * 2 + t], acc);
    out[(size_t)g * 2 + t] = acc;
  }
}

extern "C" void kernel_launch(void* const* d_in, const int* in_sizes, int n_in,
                              void* d_out, int out_size, void* d_ws, size_t ws_size,
                              hipStream_t stream) {
  (void)n_in; (void)ws_size;
  const float* x     = (const float*)d_in[0];
  const int*   ei    = (const int*)d_in[1];
  const int*   batch = (const int*)d_in[2];
  const float* rst   = (const float*)d_in[3];
  const float* W1    = (const float*)d_in[5];
  // d_in[6] = b1 — cancels in BatchNorm, skipped
  const float* gamma = (const float*)d_in[7];
  const float* beta  = (const float*)d_in[8];
  const float* W2    = (const float*)d_in[9];
  const float* b2    = (const float*)d_in[10];
  const float* Wg    = (const float*)d_in[11];
  const float* bg    = (const float*)d_in[12];
  const float* Wr    = (const float*)d_in[13];
  const float* br    = (const float*)d_in[14];
  const float* Wc    = (const float*)d_in[15];
  const float* bc    = (const float*)d_in[16];
  float* out = (float*)d_out;

  int N = in_sizes[0] / 128;
  int E = in_sizes[1] / 2;
  int G = out_size / 2;
  const int* esrc = ei;
  const int* edst = ei + E;

  int nbkt = (N + 511) >> BKT_SHIFT;           // 196 for N=100000
  int ntiles = (E + TILE_E - 1) / TILE_E;      // 400 for E=1.6M
  int tlen = nbkt * ntiles;                    // 78400

  char* ws = (char*)d_ws;
  size_t off = 0;
  auto alloc = [&](size_t bytes) -> void* {
    void* p = ws + off;
    off += (bytes + 255) & ~(size_t)255;
    return p;
  };
  unsigned* hb  = (unsigned*)alloc((size_t)N * 64 * 4);  // packed bf16 g1/g2
  unsigned* agb = (unsigned*)alloc((size_t)N * 64 * 4);  // agg1b -> y1 -> agg2b
  int* sorted   = (int*)alloc((size_t)E * 4);
  int2* pedge   = (int2*)alloc((size_t)E * 8);           // bucket-grouped (src,dst)
  int* tcnt     = (int*)alloc((size_t)tlen * 4);
  int* toff     = (int*)alloc((size_t)tlen * 4);
  int* counts   = (int*)alloc((size_t)N * 4);
  int* cursor   = (int*)alloc((size_t)N * 4);             // row STARTS (pristine)
  float* dinv   = (float*)alloc((size_t)N * 4);
  float* stats  = (float*)alloc(256 * 4);
  int* gstart   = (int*)alloc((size_t)(G + 1) * 4);
  float* pooled = (float*)alloc((size_t)G * 128 * 4);
  int* bsum     = (int*)alloc(256 * 4);
  int* boff     = (int*)alloc(256 * 4);
  int* tbsum    = (int*)alloc(256 * 4);
  int* tboff    = (int*)alloc(256 * 4);

  int nb = (N + 255) / 256;
  int nscan = (N + 1023) / 1024;
  int ntscan = (tlen + 1023) / 1024;

  init_kernel<<<1, 256, 0, stream>>>(stats);
  // radix pass: bucket-group edges by dst>>9 (all stores coalesced)
  tile_hist_kernel<<<ntiles, 256, 0, stream>>>(edst, tcnt, E, ntiles, nbkt);
  scan1_kernel<<<ntscan, 1024, 0, stream>>>(tcnt, toff, tbsum, tlen);
  scan2_kernel<<<1, 256, 0, stream>>>(tbsum, tboff, ntscan);
  scan3_kernel<<<(tlen + 255) / 256, 256, 0, stream>>>(toff, tboff, tlen);
  tile_scatter_kernel<<<ntiles, 256, 0, stream>>>(esrc, edst, toff, pedge, E, ntiles, nbkt);
  // degrees + CSR offsets
  deg_count_kernel<<<nbkt, 256, 0, stream>>>(pedge, toff, counts, E, ntiles, nbkt, N);
  dinv_kernel<<<nb, 256, 0, stream>>>(counts, dinv, N);
  scan1_kernel<<<nscan, 1024, 0, stream>>>(counts, cursor, bsum, N);
  scan2_kernel<<<1, 256, 0, stream>>>(bsum, boff, nscan);
  scan3_kernel<<<(N + 255) / 256, 256, 0, stream>>>(cursor, boff, N);
  // exact per-bucket counting sort (sequential writes)
  bucket_sort_kernel<<<nbkt, 256, 0, stream>>>(pedge, toff, cursor, sorted, E, ntiles, nbkt, N);

  gemm_mfma_kernel<false><<<1024, 256, 0, stream>>>(x, W1, dinv, hb, N);
  gather_kernel<<<4096, 256, 0, stream>>>(hb, sorted, cursor, counts, dinv, agb, N);

  bn_stats_kernel<<<512, 256, 0, stream>>>(agb, stats, N);
  bn_relu_kernel<<<2048, 256, 0, stream>>>(agb, stats, gamma, beta, N);

  gemm_mfma_kernel<true><<<1024, 256, 0, stream>>>(agb, W2, dinv, hb, N);
  gather_kernel<<<4096, 256, 0, stream>>>(hb, sorted, cursor, counts, dinv, agb, N);

  gstart_kernel<<<(G + 1 + 255) / 256, 256, 0, stream>>>(batch, gstart, N, G);
  pool_kernel<<<G, 256, 0, stream>>>(agb, gstart, b2, pooled, G);
  head_kernel<<<G, 128, 0, stream>>>(pooled, rst, Wg, bg, Wr, br, Wc, bc, out, G);
}

// Round 8
// 441.133 us; speedup vs baseline: 1.2921x; 1.0068x over previous
//
#include <hip/hip_runtime.h>

// Pipeline (node features packed bf16 pairs; word c = channels 2c,2c+1):
//  tile_hist (+stats zero) -> scan(tcnt) -> tile_scatter (radix: edges bucket-
//  grouped by dst>>9, ALL stores coalesced) -> deg_count (+dinv fused)
//  -> scan(counts) -> bucket_sort (LDS counting sort per 512-node bucket,
//  sequential writes -> sorted[] CSR; cursor stays row-starts)
//  -> gemm_mfma<f32 A> (g1 = dinv .* bf16(x@W1); b1 cancels in BN)
//  -> gather (agg1b = di*(sum g1[src] + g1[i]))  [dwordx4: 4 edges/load]
//  -> bn_stats -> bn_relu (in place)
//  -> gemm_mfma<bf16 A> (g2) -> gather (agg2b)
//  -> gstart -> pool (+b2) -> head
//
// HW laws measured this session:
//  - scattered dword stores: ~40-64B HBM writeback each; L2 never assembles
//    lines -> all sort-pipeline stores are sequential.
//  - gather FETCH floor = 8 XCD x table size (L2 catches all intra-XCD reuse);
//    gather is latency/MLP-bound, hence 4-edges-per-dwordx4 below.

typedef __attribute__((ext_vector_type(8))) short bf16x8;
typedef __attribute__((ext_vector_type(4))) float f32x4;
typedef __attribute__((ext_vector_type(4))) unsigned u32x4;

#define NBKT_MAX 256
#define BKT_SHIFT 9            // bucket = dst >> 9 (512 nodes per bucket)
#define TILE_E 4000            // edges per radix tile
#define BSORT_CAP 12544        // LDS staging cap per bucket

__device__ __forceinline__ float bf_lo(unsigned u) {
  union { unsigned u; float f; } c; c.u = u << 16; return c.f;
}
__device__ __forceinline__ float bf_hi(unsigned u) {
  union { unsigned u; float f; } c; c.u = u & 0xffff0000u; return c.f;
}
__device__ __forceinline__ unsigned short f32_bf16(float f) {
  union { float f; unsigned u; } c; c.f = f;
  return (unsigned short)((c.u + 0x7fffu + ((c.u >> 16) & 1u)) >> 16);  // RNE
}
__device__ __forceinline__ unsigned pack_bf16(float a, float b) {
  return (unsigned)f32_bf16(a) | ((unsigned)f32_bf16(b) << 16);
}

// ---- radix pass A: per-tile bucket histogram (+ zero stats, saves a launch) ----
__global__ __launch_bounds__(256) void tile_hist_kernel(const int* __restrict__ dst,
                                                        int* __restrict__ tcnt,
                                                        float* __restrict__ stats,
                                                        int e, int ntiles, int nbkt) {
  __shared__ int hist[NBKT_MAX];
  int tile = blockIdx.x;
  if (tile == 0) stats[threadIdx.x] = 0.f;  // 256 floats
  for (int b = threadIdx.x; b < nbkt; b += 256) hist[b] = 0;
  __syncthreads();
  int t0 = tile * TILE_E;
  int tend = t0 + TILE_E; if (tend > e) tend = e;
  for (int i = t0 + threadIdx.x; i < tend; i += 256)
    atomicAdd(&hist[__builtin_nontemporal_load(&dst[i]) >> BKT_SHIFT], 1);
  __syncthreads();
  for (int b = threadIdx.x; b < nbkt; b += 256) tcnt[b * ntiles + tile] = hist[b];
}

// ---- radix pass A scatter: LDS-staged bucket grouping, coalesced writes ----
__global__ __launch_bounds__(256) void tile_scatter_kernel(const int* __restrict__ src,
                                                           const int* __restrict__ dst,
                                                           const int* __restrict__ toff,
                                                           int2* __restrict__ pedge,
                                                           int e, int ntiles, int nbkt) {
  __shared__ int hist[NBKT_MAX], cnt[NBKT_MAX], gbase[NBKT_MAX];
  __shared__ int2 led[TILE_E];
  int tile = blockIdx.x;
  for (int b = threadIdx.x; b < nbkt; b += 256) { hist[b] = 0; cnt[b] = 0; }
  __syncthreads();
  int t0 = tile * TILE_E;
  int tend = t0 + TILE_E; if (tend > e) tend = e;
  for (int i = t0 + threadIdx.x; i < tend; i += 256)
    atomicAdd(&hist[__builtin_nontemporal_load(&dst[i]) >> BKT_SHIFT], 1);
  __syncthreads();
  if (threadIdx.x == 0) {
    int run = 0;
    for (int b = 0; b < nbkt; ++b) { int t = hist[b]; hist[b] = run; run += t; }
  }
  for (int b = threadIdx.x; b < nbkt; b += 256) gbase[b] = toff[b * ntiles + tile];
  __syncthreads();
  for (int i = t0 + threadIdx.x; i < tend; i += 256) {
    int s = __builtin_nontemporal_load(&src[i]);
    int d = __builtin_nontemporal_load(&dst[i]);
    int bkt = d >> BKT_SHIFT;
    int slot = hist[bkt] + atomicAdd(&cnt[bkt], 1);
    led[slot] = make_int2(s, d);
  }
  __syncthreads();
  int tcount = tend - t0;
  for (int j = threadIdx.x; j < tcount; j += 256) {
    int2 sd = led[j];
    int bkt = sd.y >> BKT_SHIFT;
    pedge[gbase[bkt] + (j - hist[bkt])] = sd;  // runs of ~20 int2 -> full lines
  }
}

// ---- per-bucket degree count via LDS histogram, dinv fused ----
__global__ __launch_bounds__(256) void deg_count_kernel(const int2* __restrict__ pedge,
                                                        const int* __restrict__ toff,
                                                        int* __restrict__ counts,
                                                        float* __restrict__ dinv,
                                                        int e, int ntiles, int nbkt, int n) {
  __shared__ int cnt[512];
  int b = blockIdx.x;
  int nb0 = b << BKT_SHIFT;
  int nn = n - nb0; if (nn > 512) nn = 512;
  for (int l = threadIdx.x; l < 512; l += 256) cnt[l] = 0;
  __syncthreads();
  int estart = toff[b * ntiles];
  int eend = (b + 1 < nbkt) ? toff[(b + 1) * ntiles] : e;
  for (int i = estart + threadIdx.x; i < eend; i += 256)
    atomicAdd(&cnt[pedge[i].y - nb0], 1);
  __syncthreads();
  for (int l = threadIdx.x; l < nn; l += 256) {
    int c = cnt[l];
    counts[nb0 + l] = c;
    dinv[nb0 + l] = rsqrtf((float)(c + 1));  // +1 self-loop
  }
}

// ---- hierarchical exclusive scan ----
__global__ __launch_bounds__(1024) void scan1_kernel(const int* __restrict__ counts,
                                                     int* __restrict__ cursor,
                                                     int* __restrict__ bsum, int n) {
  __shared__ int wsum[16];
  int tid = threadIdx.x, lane = tid & 63, wid = tid >> 6;
  int idx = blockIdx.x * 1024 + tid;
  int orig = (idx < n) ? counts[idx] : 0;
  int v = orig;
#pragma unroll
  for (int d = 1; d < 64; d <<= 1) {
    int t = __shfl_up(v, d, 64);
    if (lane >= d) v += t;
  }
  if (lane == 63) wsum[wid] = v;
  __syncthreads();
  if (wid == 0 && lane < 16) {
    int s = wsum[lane];
#pragma unroll
    for (int d = 1; d < 16; d <<= 1) {
      int t = __shfl_up(s, d, 64);
      if (lane >= d) s += t;
    }
    wsum[lane] = s;
  }
  __syncthreads();
  int wexcl = (wid == 0) ? 0 : wsum[wid - 1];
  if (idx < n) cursor[idx] = wexcl + (v - orig);
  if (tid == 0) bsum[blockIdx.x] = wsum[15];
}

__global__ __launch_bounds__(256) void scan2_kernel(const int* __restrict__ bsum,
                                                    int* __restrict__ boff, int nb) {
  __shared__ int wsum[4];
  int tid = threadIdx.x, lane = tid & 63, wid = tid >> 6;
  int orig = (tid < nb) ? bsum[tid] : 0;
  int v = orig;
#pragma unroll
  for (int d = 1; d < 64; d <<= 1) {
    int t = __shfl_up(v, d, 64);
    if (lane >= d) v += t;
  }
  if (lane == 63) wsum[wid] = v;
  __syncthreads();
  if (tid == 0) {
    int run = 0;
#pragma unroll
    for (int w = 0; w < 4; ++w) { int t = wsum[w]; wsum[w] = run; run += t; }
  }
  __syncthreads();
  if (tid < nb) boff[tid] = wsum[wid] + (v - orig);
}

__global__ void scan3_kernel(int* __restrict__ cursor, const int* __restrict__ boff, int n) {
  int i = blockIdx.x * blockDim.x + threadIdx.x;
  if (i < n) cursor[i] += boff[i >> 10];
}

// ---- final exact counting sort per 512-node bucket, all-sequential writes ----
__global__ __launch_bounds__(256) void bucket_sort_kernel(const int2* __restrict__ pedge,
                                                          const int* __restrict__ toff,
                                                          const int* __restrict__ cursor,
                                                          int* __restrict__ sorted_src,
                                                          int e, int ntiles, int nbkt, int n) {
  __shared__ int lcur[512];
  __shared__ int lsrc[BSORT_CAP];
  int b = blockIdx.x;
  int nb0 = b << BKT_SHIFT;
  int nn = n - nb0; if (nn > 512) nn = 512;
  int estart = toff[b * ntiles];
  int eend = (b + 1 < nbkt) ? toff[(b + 1) * ntiles] : e;
  for (int l = threadIdx.x; l < nn; l += 256) lcur[l] = cursor[nb0 + l] - estart;
  __syncthreads();
  for (int i = estart + threadIdx.x; i < eend; i += 256) {
    int2 sd = pedge[i];
    int pos = atomicAdd(&lcur[sd.y - nb0], 1);
    if (pos < BSORT_CAP) lsrc[pos] = sd.x;
  }
  __syncthreads();
  int cnt = eend - estart;
  if (cnt > BSORT_CAP) cnt = BSORT_CAP;
  for (int j = threadIdx.x; j < cnt; j += 256) sorted_src[estart + j] = lsrc[j];
}

// MFMA GEMM + dinv row-scale epilogue: Cb[n][64 words] = bf16(dinv[r] * (A@W)[r][:]).
template <bool ABF16>
__global__ __launch_bounds__(256) void gemm_mfma_kernel(const void* __restrict__ Ap,
                                                        const float* __restrict__ W,
                                                        const float* __restrict__ dinv,
                                                        unsigned* __restrict__ Cb, int n) {
  __shared__ unsigned short WB[16384];  // [kt][ct][nl][q][8 bf16] = 32 KB
  int tid = threadIdx.x;
  for (int idx = tid; idx < 16384; idx += 256) {
    int k = idx >> 7, c = idx & 127;  // W[k][c]
    int kt = k >> 5, q = (k >> 3) & 3, j = k & 7;
    int ct = c >> 4, nl = c & 15;
    WB[(((kt * 8 + ct) * 16 + nl) * 4 + q) * 8 + j] = f32_bf16(W[idx]);
  }
  __syncthreads();
  int lane = tid & 63;
  int m = lane & 15, q = lane >> 4;
  int wv = (int)((blockIdx.x * 256u + tid) >> 6);
  int nwv = (int)((gridDim.x * 256u) >> 6);
  int ntiles = n >> 4;  // n % 16 == 0 here (100000)
  for (int t = wv; t < ntiles; t += nwv) {
    int row = t * 16 + m;
    bf16x8 af[4];
    if (ABF16) {
      const bf16x8* Ar = (const bf16x8*)((const unsigned*)Ap + (size_t)row * 64 + q * 4);
#pragma unroll
      for (int kt = 0; kt < 4; ++kt) af[kt] = Ar[kt * 4];
    } else {
      const float* Arow = (const float*)Ap + (size_t)row * 128 + q * 8;
#pragma unroll
      for (int kt = 0; kt < 4; ++kt) {
        f32x4 a0 = *(const f32x4*)(Arow + kt * 32);
        f32x4 a1 = *(const f32x4*)(Arow + kt * 32 + 4);
        union { bf16x8 v; unsigned short s[8]; } u;
        u.s[0] = f32_bf16(a0.x); u.s[1] = f32_bf16(a0.y);
        u.s[2] = f32_bf16(a0.z); u.s[3] = f32_bf16(a0.w);
        u.s[4] = f32_bf16(a1.x); u.s[5] = f32_bf16(a1.y);
        u.s[6] = f32_bf16(a1.z); u.s[7] = f32_bf16(a1.w);
        af[kt] = u.v;
      }
    }
    f32x4 acc[8];
#pragma unroll
    for (int ct = 0; ct < 8; ++ct) acc[ct] = (f32x4){0.f, 0.f, 0.f, 0.f};
#pragma unroll
    for (int kt = 0; kt < 4; ++kt) {
#pragma unroll
      for (int ct = 0; ct < 8; ++ct) {
        bf16x8 b = *(const bf16x8*)&WB[(((kt * 8 + ct) * 16 + m) * 4 + q) * 8];
        acc[ct] = __builtin_amdgcn_mfma_f32_16x16x32_bf16(af[kt], b, acc[ct], 0, 0, 0);
      }
    }
#pragma unroll
    for (int r4 = 0; r4 < 4; ++r4) {
      int r = t * 16 + q * 4 + r4;
      float dv = dinv[r];
#pragma unroll
      for (int ct = 0; ct < 8; ++ct) {
        float v = acc[ct][r4] * dv;
        float p = __shfl_xor(v, 1, 64);
        if (!(m & 1))
          Cb[(size_t)r * 64 + ct * 8 + (m >> 1)] = pack_bf16(v, p);
      }
    }
  }
}

// agg[i] = dinv[i] * ( g[i] + sum_e g[src_e] ), g pre-scaled by dinv in GEMM.
// dwordx4 structure: 16 lanes x 16B = one 256B row, so one wave-load fetches
// 4 items' rows (item = lane>>4). Items 0..cnt-1 = edges, item cnt = self.
// 8 fp32 acc/lane; one shfl_xor(16,32) reduce per NODE. Unroll 4 quads ->
// 16 rows in flight per wave.
__global__ __launch_bounds__(256) void gather_kernel(const unsigned* __restrict__ g,
    const int* __restrict__ srcs, const int* __restrict__ cursor,
    const int* __restrict__ counts, const float* __restrict__ dinv,
    unsigned* __restrict__ out, int n) {
  int lane = threadIdx.x & 63;
  int grp = lane >> 4;   // item within quad
  int sub = lane & 15;   // 16B sub-block within row (words 4*sub..4*sub+3)
  int gw = (int)((blockIdx.x * blockDim.x + threadIdx.x) >> 6);
  int nw = (int)((gridDim.x * blockDim.x) >> 6);
  for (int i0 = gw; i0 < n; i0 += nw) {
    int i = __builtin_amdgcn_readfirstlane(i0);
    int beg = cursor[i];
    int cnt = counts[i];
    int cnt2 = cnt + 1;  // + self item (k == cnt)
    float di = dinv[i];
    float a0 = 0.f, a1 = 0.f, a2 = 0.f, a3 = 0.f;
    float a4 = 0.f, a5 = 0.f, a6 = 0.f, a7 = 0.f;
    int e = 0;
    // 4 quads (16 items) per iteration: all items valid (k <= cnt).
    for (; e + 16 <= cnt2; e += 16) {
      int kA = e + grp, kB = kA + 4, kC = kA + 8, kD = kA + 12;
      int lA = srcs[beg + kA];  // k==cnt reads 1 past row end (slack), masked below
      int lB = srcs[beg + kB];
      int lC = srcs[beg + kC];
      int lD = srcs[beg + kD];
      int sA = (kA < cnt) ? lA : i;
      int sB = (kB < cnt) ? lB : i;
      int sC = (kC < cnt) ? lC : i;
      int sD = (kD < cnt) ? lD : i;
      u32x4 vA = *((const u32x4*)(g + ((size_t)sA << 6)) + sub);
      u32x4 vB = *((const u32x4*)(g + ((size_t)sB << 6)) + sub);
      u32x4 vC = *((const u32x4*)(g + ((size_t)sC << 6)) + sub);
      u32x4 vD = *((const u32x4*)(g + ((size_t)sD << 6)) + sub);
      a0 += bf_lo(vA.x); a1 += bf_hi(vA.x); a2 += bf_lo(vA.y); a3 += bf_hi(vA.y);
      a4 += bf_lo(vA.z); a5 += bf_hi(vA.z); a6 += bf_lo(vA.w); a7 += bf_hi(vA.w);
      a0 += bf_lo(vB.x); a1 += bf_hi(vB.x); a2 += bf_lo(vB.y); a3 += bf_hi(vB.y);
      a4 += bf_lo(vB.z); a5 += bf_hi(vB.z); a6 += bf_lo(vB.w); a7 += bf_hi(vB.w);
      a0 += bf_lo(vC.x); a1 += bf_hi(vC.x); a2 += bf_lo(vC.y); a3 += bf_hi(vC.y);
      a4 += bf_lo(vC.z); a5 += bf_hi(vC.z); a6 += bf_lo(vC.w); a7 += bf_hi(vC.w);
      a0 += bf_lo(vD.x); a1 += bf_hi(vD.x); a2 += bf_lo(vD.y); a3 += bf_hi(vD.y);
      a4 += bf_lo(vD.z); a5 += bf_hi(vD.z); a6 += bf_lo(vD.w); a7 += bf_hi(vD.w);
    }
    // single full quads
    for (; e + 4 <= cnt2; e += 4) {
      int k = e + grp;
      int ls = srcs[beg + k];
      int s = (k < cnt) ? ls : i;
      u32x4 v = *((const u32x4*)(g + ((size_t)s << 6)) + sub);
      a0 += bf_lo(v.x); a1 += bf_hi(v.x); a2 += bf_lo(v.y); a3 += bf_hi(v.y);
      a4 += bf_lo(v.z); a5 += bf_hi(v.z); a6 += bf_lo(v.w); a7 += bf_hi(v.w);
    }
    // partial quad: mask items k >= cnt2
    if (e < cnt2) {
      int k = e + grp;
      int kk = (k < cnt) ? k : 0;
      int ls = srcs[beg + kk];
      int s = (k < cnt) ? ls : i;
      float sel = (k < cnt2) ? 1.f : 0.f;
      u32x4 v = *((const u32x4*)(g + ((size_t)s << 6)) + sub);
      a0 = fmaf(sel, bf_lo(v.x), a0); a1 = fmaf(sel, bf_hi(v.x), a1);
      a2 = fmaf(sel, bf_lo(v.y), a2); a3 = fmaf(sel, bf_hi(v.y), a3);
      a4 = fmaf(sel, bf_lo(v.z), a4); a5 = fmaf(sel, bf_hi(v.z), a5);
      a6 = fmaf(sel, bf_lo(v.w), a7 * 0.f + a6); a7 = fmaf(sel, bf_hi(v.w), a7);
    }
    // reduce the 4 item-groups
    a0 += __shfl_xor(a0, 16, 64); a0 += __shfl_xor(a0, 32, 64);
    a1 += __shfl_xor(a1, 16, 64); a1 += __shfl_xor(a1, 32, 64);
    a2 += __shfl_xor(a2, 16, 64); a2 += __shfl_xor(a2, 32, 64);
    a3 += __shfl_xor(a3, 16, 64); a3 += __shfl_xor(a3, 32, 64);
    a4 += __shfl_xor(a4, 16, 64); a4 += __shfl_xor(a4, 32, 64);
    a5 += __shfl_xor(a5, 16, 64); a5 += __shfl_xor(a5, 32, 64);
    a6 += __shfl_xor(a6, 16, 64); a6 += __shfl_xor(a6, 32, 64);
    a7 += __shfl_xor(a7, 16, 64); a7 += __shfl_xor(a7, 32, 64);
    if (grp == 0) {
      u32x4 o;
      o.x = pack_bf16(di * a0, di * a1);
      o.y = pack_bf16(di * a2, di * a3);
      o.z = pack_bf16(di * a4, di * a5);
      o.w = pack_bf16(di * a6, di * a7);
      *((u32x4*)(out + ((size_t)i << 6)) + sub) = o;
    }
  }
}

__global__ __launch_bounds__(256) void bn_stats_kernel(const unsigned* __restrict__ a,
                                                       float* __restrict__ stats, int n) {
  int c2 = threadIdx.x & 63;
  int ph = threadIdx.x >> 6;
  float s0 = 0.f, s1 = 0.f, q0 = 0.f, q1 = 0.f;
  for (int r = blockIdx.x * 4 + ph; r < n; r += gridDim.x * 4) {
    unsigned v = a[(size_t)r * 64 + c2];
    float x0 = bf_lo(v), x1 = bf_hi(v);
    s0 += x0; s1 += x1; q0 += x0 * x0; q1 += x1 * x1;
  }
  __shared__ float ls[4][64][4];
  ls[ph][c2][0] = s0; ls[ph][c2][1] = s1; ls[ph][c2][2] = q0; ls[ph][c2][3] = q1;
  __syncthreads();
  if (threadIdx.x < 64) {
    int c = threadIdx.x;
    float S0 = 0.f, S1 = 0.f, Q0 = 0.f, Q1 = 0.f;
#pragma unroll
    for (int p = 0; p < 4; ++p) {
      S0 += ls[p][c][0]; S1 += ls[p][c][1]; Q0 += ls[p][c][2]; Q1 += ls[p][c][3];
    }
    atomicAdd(&stats[2 * c], S0);
    atomicAdd(&stats[2 * c + 1], S1);
    atomicAdd(&stats[128 + 2 * c], Q0);
    atomicAdd(&stats[129 + 2 * c], Q1);
  }
}

// In-place y = bf16(relu(gamma*(a-mu)*rstd + beta)); packed.
__global__ __launch_bounds__(256) void bn_relu_kernel(unsigned* __restrict__ a,
    const float* __restrict__ stats, const float* __restrict__ gamma,
    const float* __restrict__ beta, int n) {
  __shared__ float sc[128], sh[128];
  int tid = threadIdx.x;
  if (tid < 128) {
    float invN = 1.f / (float)n;
    float mu = stats[tid] * invN;
    float var = stats[128 + tid] * invN - mu * mu;
    float rstd = rsqrtf(var + 1e-5f);
    float s = gamma[tid] * rstd;
    sc[tid] = s;
    sh[tid] = beta[tid] - mu * s;
  }
  __syncthreads();
  size_t total = (size_t)n * 64;
  for (size_t w = blockIdx.x * (size_t)blockDim.x + tid; w < total;
       w += (size_t)gridDim.x * blockDim.x) {
    int c2 = (int)(w & 63);
    unsigned v = a[w];
    float y0 = fmaxf(fmaf(sc[2 * c2], bf_lo(v), sh[2 * c2]), 0.f);
    float y1 = fmaxf(fmaf(sc[2 * c2 + 1], bf_hi(v), sh[2 * c2 + 1]), 0.f);
    a[w] = pack_bf16(y0, y1);
  }
}

__global__ void gstart_kernel(const int* __restrict__ batch, int* __restrict__ gstart,
                              int n, int G) {
  int g = blockIdx.x * blockDim.x + threadIdx.x;
  if (g > G) return;
  if (g == G) { gstart[g] = n; return; }
  int lo = 0, hi = n;
  while (lo < hi) {
    int mid = (lo + hi) >> 1;
    if (batch[mid] < g) lo = mid + 1; else hi = mid;
  }
  gstart[g] = lo;
}

__global__ __launch_bounds__(256) void pool_kernel(const unsigned* __restrict__ a,
    const int* __restrict__ gstart, const float* __restrict__ b2,
    float* __restrict__ pooled, int G) {
  int g = blockIdx.x;
  int c2 = threadIdx.x & 63;
  int ph = threadIdx.x >> 6;
  int s = gstart[g], e = gstart[g + 1];
  float a0 = 0.f, a1 = 0.f;
  for (int r = s + ph; r < e; r += 4) {
    unsigned v = a[(size_t)r * 64 + c2];
    a0 += bf_lo(v); a1 += bf_hi(v);
  }
  __shared__ float ls[4][64][2];
  ls[ph][c2][0] = a0; ls[ph][c2][1] = a1;
  __syncthreads();
  if (threadIdx.x < 64) {
    int c = threadIdx.x;
    float S0 = 0.f, S1 = 0.f;
#pragma unroll
    for (int p = 0; p < 4; ++p) { S0 += ls[p][c][0]; S1 += ls[p][c][1]; }
    int cnt = e - s;
    float inv = (cnt > 0) ? 1.f / (float)cnt : 0.f;
    float2 res;
    res.x = (cnt > 0) ? (S0 * inv + b2[2 * c]) : 0.f;
    res.y = (cnt > 0) ? (S1 * inv + b2[2 * c + 1]) : 0.f;
    ((float2*)(pooled + (size_t)g * 128))[c] = res;
  }
}

__global__ __launch_bounds__(128) void head_kernel(const float* __restrict__ pooled,
    const float* __restrict__ rst, const float* __restrict__ Wg, const float* __restrict__ bg,
    const float* __restrict__ Wr, const float* __restrict__ br, const float* __restrict__ Wc,
    const float* __restrict__ bc, float* __restrict__ out, int G) {
  int g = blockIdx.x;
  int t = threadIdx.x;
  __shared__ float xc[128];
  if (t < 64) {
    float acc = bg[t];
    const float* __restrict__ p = pooled + (size_t)g * 128;
    for (int k = 0; k < 128; ++k) acc = fmaf(p[k], Wg[k * 64 + t], acc);
    xc[t] = fmaxf(acc, 0.f);
  } else {
    int j = t - 64;
    float acc = br[j];
    const float* __restrict__ r = rst + (size_t)g * 64;
    for (int k = 0; k < 64; ++k) acc = fmaf(r[k], Wr[k * 64 + j], acc);
    xc[t] = fmaxf(acc, 0.f);
  }
  __syncthreads();
  if (t < 2) {
    float acc = bc[t];
    for (int j = 0; j < 128; ++j) acc = fmaf(xc[j], Wc[j * 2 + t], acc);
    out[(size_t)g * 2 + t] = acc;
  }
}

extern "C" void kernel_launch(void* const* d_in, const int* in_sizes, int n_in,
                              void* d_out, int out_size, void* d_ws, size_t ws_size,
                              hipStream_t stream) {
  (void)n_in; (void)ws_size;
  const float* x     = (const float*)d_in[0];
  const int*   ei    = (const int*)d_in[1];
  const int*   batch = (const int*)d_in[2];
  const float* rst   = (const float*)d_in[3];
  const float* W1    = (const float*)d_in[5];
  // d_in[6] = b1 — cancels in BatchNorm, skipped
  const float* gamma = (const float*)d_in[7];
  const float* beta  = (const float*)d_in[8];
  const float* W2    = (const float*)d_in[9];
  const float* b2    = (const float*)d_in[10];
  const float* Wg    = (const float*)d_in[11];
  const float* bg    = (const float*)d_in[12];
  const float* Wr    = (const float*)d_in[13];
  const float* br    = (const float*)d_in[14];
  const float* Wc    = (const float*)d_in[15];
  const float* bc    = (const float*)d_in[16];
  float* out = (float*)d_out;

  int N = in_sizes[0] / 128;
  int E = in_sizes[1] / 2;
  int G = out_size / 2;
  const int* esrc = ei;
  const int* edst = ei + E;

  int nbkt = (N + 511) >> BKT_SHIFT;           // 196 for N=100000
  int ntiles = (E + TILE_E - 1) / TILE_E;      // 400 for E=1.6M
  int tlen = nbkt * ntiles;                    // 78400

  char* ws = (char*)d_ws;
  size_t off = 0;
  auto alloc = [&](size_t bytes) -> void* {
    void* p = ws + off;
    off += (bytes + 255) & ~(size_t)255;
    return p;
  };
  unsigned* hb  = (unsigned*)alloc((size_t)N * 64 * 4);  // packed bf16 g1/g2
  unsigned* agb = (unsigned*)alloc((size_t)N * 64 * 4);  // agg1b -> y1 -> agg2b
  int* sorted   = (int*)alloc((size_t)E * 4 + 256);      // +slack: gather may read 1 past
  int2* pedge   = (int2*)alloc((size_t)E * 8);           // bucket-grouped (src,dst)
  int* tcnt     = (int*)alloc((size_t)tlen * 4);
  int* toff     = (int*)alloc((size_t)tlen * 4);
  int* counts   = (int*)alloc((size_t)N * 4);
  int* cursor   = (int*)alloc((size_t)N * 4);             // row STARTS (pristine)
  float* dinv   = (float*)alloc((size_t)N * 4);
  float* stats  = (float*)alloc(256 * 4);
  int* gstart   = (int*)alloc((size_t)(G + 1) * 4);
  float* pooled = (float*)alloc((size_t)G * 128 * 4);
  int* bsum     = (int*)alloc(256 * 4);
  int* boff     = (int*)alloc(256 * 4);
  int* tbsum    = (int*)alloc(256 * 4);
  int* tboff    = (int*)alloc(256 * 4);

  int nscan = (N + 1023) / 1024;
  int ntscan = (tlen + 1023) / 1024;

  // radix pass: bucket-group edges by dst>>9 (all stores coalesced)
  tile_hist_kernel<<<ntiles, 256, 0, stream>>>(edst, tcnt, stats, E, ntiles, nbkt);
  scan1_kernel<<<ntscan, 1024, 0, stream>>>(tcnt, toff, tbsum, tlen);
  scan2_kernel<<<1, 256, 0, stream>>>(tbsum, tboff, ntscan);
  scan3_kernel<<<(tlen + 255) / 256, 256, 0, stream>>>(toff, tboff, tlen);
  tile_scatter_kernel<<<ntiles, 256, 0, stream>>>(esrc, edst, toff, pedge, E, ntiles, nbkt);
  // degrees (+dinv) + CSR offsets
  deg_count_kernel<<<nbkt, 256, 0, stream>>>(pedge, toff, counts, dinv, E, ntiles, nbkt, N);
  scan1_kernel<<<nscan, 1024, 0, stream>>>(counts, cursor, bsum, N);
  scan2_kernel<<<1, 256, 0, stream>>>(bsum, boff, nscan);
  scan3_kernel<<<(N + 255) / 256, 256, 0, stream>>>(cursor, boff, N);
  // exact per-bucket counting sort (sequential writes)
  bucket_sort_kernel<<<nbkt, 256, 0, stream>>>(pedge, toff, cursor, sorted, E, ntiles, nbkt, N);

  gemm_mfma_kernel<false><<<1024, 256, 0, stream>>>(x, W1, dinv, hb, N);
  gather_kernel<<<4096, 256, 0, stream>>>(hb, sorted, cursor, counts, dinv, agb, N);

  bn_stats_kernel<<<512, 256, 0, stream>>>(agb, stats, N);
  bn_relu_kernel<<<2048, 256, 0, stream>>>(agb, stats, gamma, beta, N);

  gemm_mfma_kernel<true><<<1024, 256, 0, stream>>>(agb, W2, dinv, hb, N);
  gather_kernel<<<4096, 256, 0, stream>>>(hb, sorted, cursor, counts, dinv, agb, N);

  gstart_kernel<<<(G + 1 + 255) / 256, 256, 0, stream>>>(batch, gstart, N, G);
  pool_kernel<<<G, 256, 0, stream>>>(agb, gstart, b2, pooled, G);
  head_kernel<<<G, 128, 0, stream>>>(pooled, rst, Wg, bg, Wr, br, Wc, bc, out, G);
}